// Round 1
// baseline (2142.694 us; speedup 1.0000x reference)
//
#include <hip/hip_runtime.h>

#define NSEQ 576
#define CDIM 256
#define HEADS 3
#define HD 64
#define FEAT 192      // HEADS*HD
#define QKVF 576      // 3*FEAT
#define VP 70         // HD+6
#define BHN 192       // 64*3
#define DIMSZ 29400   // 2*3*70*70

// ---- positional encoding: pos[n] = {py^2, px^2, py*px, py, px, 1},
//      py = ys[n%24], px = xs[n/24], linspace(-1,1,24)
__device__ __forceinline__ float posval(int n, int pe){
  int yi = n % 24, xi = n / 24;
  float py = (float)yi * (2.0f/23.0f) - 1.0f;
  float px = (float)xi * (2.0f/23.0f) - 1.0f;
  switch(pe){
    case 0: return py*py;
    case 1: return px*px;
    case 2: return py*px;
    case 3: return py;
    case 4: return px;
    default: return 1.0f;
  }
}

// ---- K0: LayerNorm stats (mu, rstd) per (input, b, n); row = x[i][b][:,n] over C
__global__ __launch_bounds__(192) void k_ln_stats(const float* __restrict__ x1, const float* __restrict__ x2,
                                                  float* __restrict__ mu, float* __restrict__ rstd){
  int idx = blockIdx.x;                 // 2*64*3 = 384
  int i2 = idx / 192;
  int rem = idx % 192;
  int b = rem / 3, ng = rem % 3;
  int n = ng * 192 + threadIdx.x;
  const float* x = i2 ? x2 : x1;
  const float* xb = x + (size_t)b * CDIM * NSEQ + n;
  float s = 0.f, sq = 0.f;
  for (int c = 0; c < CDIM; ++c){
    float v = xb[(size_t)c * NSEQ];
    s += v; sq += v * v;
  }
  float m = s * (1.0f/256.0f);
  float var = sq * (1.0f/256.0f) - m * m;
  int o = (i2 * 64 + b) * NSEQ + n;
  mu[o] = m;
  rstd[o] = rsqrtf(var + 1e-5f);
}

// ---- K0b: transpose qkv_w [576,256] -> wT [256,576]
__global__ __launch_bounds__(256) void k_transpose_w(const float* __restrict__ w, float* __restrict__ wT){
  int f = blockIdx.x;        // 576
  int c = threadIdx.x;       // 256
  wT[(size_t)c * QKVF + f] = w[(size_t)f * CDIM + c];
}

// ---- K1: fused LN + QKV GEMM.  out qkv[i][b][n][f], f = which*192 + h*64 + d
// M = 2*64*576 = 73728 rows, N = 576, K = 256. 64x64 tile, BK=16, 4x4 microtile.
__global__ __launch_bounds__(256) void k_qkv_gemm(const float* __restrict__ x1, const float* __restrict__ x2,
                                                  const float* __restrict__ mu, const float* __restrict__ rstd,
                                                  const float* __restrict__ lnw, const float* __restrict__ lnb,
                                                  const float* __restrict__ wT, float* __restrict__ qkv){
  int wg = blockIdx.x;               // 1152*9
  int ft = wg % 9;
  int mt = wg / 9;
  int ibn = mt * 64;
  int i2 = ibn / (64 * NSEQ);
  int bn = ibn % (64 * NSEQ);
  int b  = bn / NSEQ;
  int n0 = bn % NSEQ;                // 576 % 64 == 0: tile never crosses (i,b)
  const float* x = i2 ? x2 : x1;
  const float* xb = x + (size_t)b * CDIM * NSEQ + n0;
  __shared__ __align__(16) float As[16][72];
  __shared__ __align__(16) float Bs[16][72];
  __shared__ float smu[64], srstd[64];
  int t = threadIdx.x, tx = t & 15, ty = t >> 4;
  if (t < 64){ smu[t] = mu[ibn + t]; srstd[t] = rstd[ibn + t]; }
  float acc[4][4] = {};
  for (int k0 = 0; k0 < CDIM; k0 += 16){
    __syncthreads();
    #pragma unroll
    for (int r = 0; r < 4; ++r){
      int l = t + 256 * r;
      int m = l & 63, k = l >> 6;
      float v = xb[(size_t)(k0 + k) * NSEQ + m];
      As[k][m] = (v - smu[m]) * srstd[m] * lnw[k0 + k] + lnb[k0 + k];
      Bs[k][m] = wT[(size_t)(k0 + k) * QKVF + ft * 64 + m];
    }
    __syncthreads();
    #pragma unroll
    for (int k = 0; k < 16; ++k){
      float4 a4 = *(const float4*)&As[k][ty * 4];
      float4 b4 = *(const float4*)&Bs[k][tx * 4];
      float aa[4] = {a4.x, a4.y, a4.z, a4.w};
      float bb[4] = {b4.x, b4.y, b4.z, b4.w};
      #pragma unroll
      for (int i = 0; i < 4; ++i)
        #pragma unroll
        for (int j = 0; j < 4; ++j)
          acc[i][j] += aa[i] * bb[j];
    }
  }
  #pragma unroll
  for (int i = 0; i < 4; ++i){
    float4 st = make_float4(acc[i][0], acc[i][1], acc[i][2], acc[i][3]);
    *(float4*)&qkv[(size_t)(ibn + ty * 4 + i) * QKVF + ft * 64 + tx * 4] = st;
  }
}

// ---- K2: attention stats. For each (map,bh): a = q.k^T * 0.125 (map0: q2.k1, map1: q1.k2).
// Tile (nt,mt) computes exp(a) partial row sums (over its 64 m) -> rs_part[...][mt][n]
// and partial col sums (over its 64 n) -> cs_part[...][nt][m]. Deterministic, no atomics.
__global__ __launch_bounds__(256) void k_attn_stats(const float* __restrict__ qkv,
                                                    float* __restrict__ rs_part, float* __restrict__ cs_part){
  int wg = blockIdx.x;               // 2*192*81
  int map = wg / (BHN * 81);
  int r   = wg % (BHN * 81);
  int bh = r / 81, tt = r % 81;
  int nt = tt / 9, mt = tt % 9;
  int b = bh / 3, h = bh % 3;
  int qi = 1 - map, ki = map;
  const float* qb = qkv + (size_t)(qi * 64 + b) * NSEQ * QKVF + h * HD;
  const float* kb = qkv + (size_t)(ki * 64 + b) * NSEQ * QKVF + FEAT + h * HD;
  int n0 = nt * 64, m0 = mt * 64;
  __shared__ __align__(16) float Qs[16][72];
  __shared__ __align__(16) float Ks[16][72];
  __shared__ float red[64][17];
  int t = threadIdx.x, tx = t & 15, ty = t >> 4;
  float acc[4][4] = {};
  for (int d0 = 0; d0 < HD; d0 += 16){
    __syncthreads();
    #pragma unroll
    for (int rr = 0; rr < 4; ++rr){
      int l = t + 256 * rr;
      int d = l & 15, row = l >> 4;
      Qs[d][row] = qb[(size_t)(n0 + row) * QKVF + d0 + d];
      Ks[d][row] = kb[(size_t)(m0 + row) * QKVF + d0 + d];
    }
    __syncthreads();
    #pragma unroll
    for (int d = 0; d < 16; ++d){
      float4 a4 = *(const float4*)&Qs[d][ty * 4];
      float4 b4 = *(const float4*)&Ks[d][tx * 4];
      float aa[4] = {a4.x, a4.y, a4.z, a4.w};
      float bb[4] = {b4.x, b4.y, b4.z, b4.w};
      #pragma unroll
      for (int i = 0; i < 4; ++i)
        #pragma unroll
        for (int j = 0; j < 4; ++j)
          acc[i][j] += aa[i] * bb[j];
    }
  }
  float e[4][4];
  #pragma unroll
  for (int i = 0; i < 4; ++i)
    #pragma unroll
    for (int j = 0; j < 4; ++j)
      e[i][j] = __expf(acc[i][j] * 0.125f);
  // row sums (over tile's m); reduce across the 16-lane tx group
  #pragma unroll
  for (int i = 0; i < 4; ++i){
    float s = e[i][0] + e[i][1] + e[i][2] + e[i][3];
    s += __shfl_down(s, 8, 16);
    s += __shfl_down(s, 4, 16);
    s += __shfl_down(s, 2, 16);
    s += __shfl_down(s, 1, 16);
    if (tx == 0) rs_part[((size_t)(map * BHN + bh) * 9 + mt) * NSEQ + n0 + ty * 4 + i] = s;
  }
  // col sums (over tile's n); reduce across ty via LDS
  #pragma unroll
  for (int j = 0; j < 4; ++j)
    red[tx * 4 + j][ty] = e[0][j] + e[1][j] + e[2][j] + e[3][j];
  __syncthreads();
  if (t < 64){
    float s = 0.f;
    #pragma unroll
    for (int u = 0; u < 16; ++u) s += red[t][u];
    cs_part[((size_t)(map * BHN + bh) * 9 + nt) * NSEQ + m0 + t] = s;
  }
}

// ---- K2b: reduce 9 partials -> rs, cs
__global__ __launch_bounds__(256) void k_stats_reduce(const float* __restrict__ rs_part, const float* __restrict__ cs_part,
                                                      float* __restrict__ rs, float* __restrict__ cs){
  int tid = blockIdx.x * 256 + threadIdx.x;
  if (tid >= 2 * BHN * NSEQ) return;
  int mb = tid / NSEQ, n = tid % NSEQ;
  float a = 0.f, c = 0.f;
  #pragma unroll
  for (int p = 0; p < 9; ++p){
    a += rs_part[((size_t)mb * 9 + p) * NSEQ + n];
    c += cs_part[((size_t)mb * 9 + p) * NSEQ + n];
  }
  rs[tid] = a;
  cs[tid] = c;
}

// ---- K3: apply pass. Per (map,bh,ntile): recompute a tiles, af = exp(2a)/(rs*cs),
//      accumulate t[64n x 70e] = sum_m af[n,m]*vp[m,e]  (vp = v ++ pos)
__global__ __launch_bounds__(256) void k_apply_t(const float* __restrict__ qkv,
                                                 const float* __restrict__ rs, const float* __restrict__ cs,
                                                 float* __restrict__ tbuf){
  int wg = blockIdx.x;                  // 2*192*9
  int map = wg / (BHN * 9);
  int r   = wg % (BHN * 9);
  int bh = r / 9, nt = r % 9;
  int b = bh / 3, h = bh % 3;
  int qi = 1 - map, ki = map, vi = map;
  int mb = map * BHN + bh;
  const float* qb = qkv + (size_t)(qi * 64 + b) * NSEQ * QKVF + h * HD;
  const float* kb = qkv + (size_t)(ki * 64 + b) * NSEQ * QKVF + FEAT + h * HD;
  const float* vb = qkv + (size_t)(vi * 64 + b) * NSEQ * QKVF + 2 * FEAT + h * HD;
  int n0 = nt * 64;
  __shared__ __align__(16) float Qs[16][72];
  __shared__ __align__(16) float Ks[16][72];
  __shared__ float afs[64][65];
  __shared__ float vps[64][72];
  __shared__ float rsv[64], csv[64];
  int t = threadIdx.x, tx = t & 15, ty = t >> 4;
  if (t < 64) rsv[t] = rs[(size_t)mb * NSEQ + n0 + t];
  int ecol[5];
  #pragma unroll
  for (int jj = 0; jj < 5; ++jj){
    int e = tx + 16 * jj;
    ecol[jj] = (e < VP) ? e : 0;
  }
  float tacc[4][5] = {};
  for (int mt = 0; mt < 9; ++mt){
    int m0 = mt * 64;
    float acc[4][4] = {};
    __syncthreads();                      // prev t-GEMM reads done before overwrites
    if (t < 64) csv[t] = cs[(size_t)mb * NSEQ + m0 + t];
    for (int d0 = 0; d0 < HD; d0 += 16){
      __syncthreads();
      #pragma unroll
      for (int rr = 0; rr < 4; ++rr){
        int l = t + 256 * rr;
        int d = l & 15, row = l >> 4;
        Qs[d][row] = qb[(size_t)(n0 + row) * QKVF + d0 + d];
        Ks[d][row] = kb[(size_t)(m0 + row) * QKVF + d0 + d];
      }
      __syncthreads();
      #pragma unroll
      for (int d = 0; d < 16; ++d){
        float4 a4 = *(const float4*)&Qs[d][ty * 4];
        float4 b4 = *(const float4*)&Ks[d][tx * 4];
        float aa[4] = {a4.x, a4.y, a4.z, a4.w};
        float bb[4] = {b4.x, b4.y, b4.z, b4.w};
        #pragma unroll
        for (int i = 0; i < 4; ++i)
          #pragma unroll
          for (int j = 0; j < 4; ++j)
            acc[i][j] += aa[i] * bb[j];
      }
    }
    // dual-softmax weight: af = exp(a)^2 / (rs[n]*cs[m]); a = dot*0.125 -> exp(dot*0.25)
    float rrow[4];
    #pragma unroll
    for (int i = 0; i < 4; ++i) rrow[i] = rsv[ty * 4 + i];
    #pragma unroll
    for (int i = 0; i < 4; ++i)
      #pragma unroll
      for (int j = 0; j < 4; ++j)
        afs[ty * 4 + i][tx * 4 + j] = __expf(acc[i][j] * 0.25f) / (rrow[i] * csv[tx * 4 + j]);
    // stage vp tile: v columns then positional columns (+ zero pad to 72)
    #pragma unroll
    for (int rr = 0; rr < 16; ++rr){
      int mm = (t >> 6) + rr * 4;
      int e = t & 63;
      vps[mm][e] = vb[(size_t)(m0 + mm) * QKVF + e];
    }
    #pragma unroll
    for (int rr = 0; rr < 2; ++rr){
      int idx = t + 256 * rr;
      int mm = idx & 63, pe = idx >> 6;
      vps[mm][64 + pe] = (pe < 6) ? posval(m0 + mm, pe) : 0.0f;
    }
    __syncthreads();
    // t-GEMM: t[n][e] += af[n][m] * vp[m][e]
    for (int m = 0; m < 64; ++m){
      float a0 = afs[ty * 4 + 0][m];
      float a1 = afs[ty * 4 + 1][m];
      float a2 = afs[ty * 4 + 2][m];
      float a3 = afs[ty * 4 + 3][m];
      #pragma unroll
      for (int jj = 0; jj < 5; ++jj){
        float v = vps[m][ecol[jj]];
        tacc[0][jj] += a0 * v;
        tacc[1][jj] += a1 * v;
        tacc[2][jj] += a2 * v;
        tacc[3][jj] += a3 * v;
      }
    }
  }
  #pragma unroll
  for (int i = 0; i < 4; ++i)
    #pragma unroll
    for (int jj = 0; jj < 5; ++jj){
      int e = tx + 16 * jj;
      if (e < VP) tbuf[((size_t)mb * NSEQ + n0 + ty * 4 + i) * VP + e] = tacc[i][jj];
    }
}

// ---- K4: f[d][e] = sum_n vp[n][d] * t[n][e] per (map,bh); write featT[k][b], k = map*14700+h*4900+d*70+e
__global__ __launch_bounds__(256) void k_f_gemm(const float* __restrict__ qkv, const float* __restrict__ tbuf,
                                                float* __restrict__ featT){
  int wg = blockIdx.x;                 // 384
  int map = wg / BHN, bh = wg % BHN;
  int b = bh / 3, h = bh % 3;
  const float* vb = qkv + (size_t)(map * 64 + b) * NSEQ * QKVF + 2 * FEAT + h * HD;
  int mb = wg;
  __shared__ float Vs[64][72];
  __shared__ float Ts[64][72];
  int t = threadIdx.x, tx = t & 15, ty = t >> 4;
  int drow[5], ecol[5];
  #pragma unroll
  for (int u = 0; u < 5; ++u){
    int d = ty + 16 * u; drow[u] = (d < VP) ? d : 0;
    int e = tx + 16 * u; ecol[u] = (e < VP) ? e : 0;
  }
  float acc[5][5] = {};
  for (int c0 = 0; c0 < NSEQ; c0 += 64){
    __syncthreads();
    #pragma unroll
    for (int rr = 0; rr < 16; ++rr){
      int nn = (t >> 6) + rr * 4;
      int e = t & 63;
      Vs[nn][e] = vb[(size_t)(c0 + nn) * QKVF + e];
    }
    #pragma unroll
    for (int rr = 0; rr < 2; ++rr){
      int idx = t + 256 * rr;
      int nn = idx & 63, pe = idx >> 6;
      Vs[nn][64 + pe] = (pe < 6) ? posval(c0 + nn, pe) : 0.0f;
    }
    for (int idx = t; idx < 64 * VP; idx += 256){
      int nn = idx / VP, e = idx % VP;
      Ts[nn][e] = tbuf[((size_t)mb * NSEQ + c0 + nn) * VP + e];
    }
    __syncthreads();
    for (int n = 0; n < 64; ++n){
      float vd[5], te[5];
      #pragma unroll
      for (int u = 0; u < 5; ++u) vd[u] = Vs[n][drow[u]];
      #pragma unroll
      for (int u = 0; u < 5; ++u) te[u] = Ts[n][ecol[u]];
      #pragma unroll
      for (int u = 0; u < 5; ++u)
        #pragma unroll
        for (int v2 = 0; v2 < 5; ++v2)
          acc[u][v2] += vd[u] * te[v2];
    }
  }
  #pragma unroll
  for (int u = 0; u < 5; ++u)
    #pragma unroll
    for (int v2 = 0; v2 < 5; ++v2){
      int d = ty + 16 * u, e = tx + 16 * v2;
      if (d < VP && e < VP)
        featT[(size_t)(map * 14700 + h * 4900 + d * VP + e) * 64 + b] = acc[u][v2];
    }
}

// ---- K5: projection partials. grid = (8 o-tiles) x (49 k-slices of 600). block 512.
__global__ __launch_bounds__(512) void k_proj_partial(const float* __restrict__ featT, const float* __restrict__ pw,
                                                      float* __restrict__ p){
  int ot = blockIdx.x & 7;
  int s  = blockIdx.x >> 3;            // 0..48
  int t = threadIdx.x;
  int b = t & 63, og = t >> 6;         // og 0..7
  int obase = ot * 64 + og * 8;
  float acc[8] = {};
  int k0 = s * 600;
  for (int k = k0; k < k0 + 600; ++k){
    float fv = featT[(size_t)k * 64 + b];
    #pragma unroll
    for (int jj = 0; jj < 8; ++jj)
      acc[jj] += fv * pw[(size_t)(obase + jj) * DIMSZ + k];
  }
  #pragma unroll
  for (int jj = 0; jj < 8; ++jj)
    p[(size_t)s * 32768 + (size_t)(obase + jj) * 64 + b] = acc[jj];
}

// ---- K6: finalize: out[b][o] = relu(sum_s p[s][o][b] + bias[o])
__global__ __launch_bounds__(256) void k_finalize(const float* __restrict__ p, const float* __restrict__ pb,
                                                  float* __restrict__ out){
  int gid = blockIdx.x * 256 + threadIdx.x;   // 32768 = b*512 + o
  int o = gid & 511, b = gid >> 9;
  float s = pb[o];
  #pragma unroll
  for (int s2 = 0; s2 < 49; ++s2)
    s += p[(size_t)s2 * 32768 + (size_t)o * 64 + b];
  out[gid] = fmaxf(s, 0.0f);
}

extern "C" void kernel_launch(void* const* d_in, const int* in_sizes, int n_in,
                              void* d_out, int out_size, void* d_ws, size_t ws_size,
                              hipStream_t stream) {
  const float* x1   = (const float*)d_in[0];
  const float* x2   = (const float*)d_in[1];
  const float* lnw  = (const float*)d_in[2];
  const float* lnb  = (const float*)d_in[3];
  const float* qkvw = (const float*)d_in[4];
  const float* pw   = (const float*)d_in[5];
  const float* pb   = (const float*)d_in[6];
  float* out = (float*)d_out;

  float* w = (float*)d_ws;
  float* mu      = w;                    // 73728
  float* rstd    = w + 73728;            // 73728
  float* wT      = w + 147456;           // 147456
  float* qkv     = w + 294912;           // 42467328
  float* rs_part = w + 42762240;         // 1990656
  float* cs_part = w + 44752896;         // 1990656
  float* rs      = w + 46743552;         // 221184
  float* cs      = w + 46964736;         // 221184
  float* tbuf    = w + 47185920;         // 15482880
  float* featT   = w + 62668800;         // 1881600
  float* p       = w + 64550400;         // 1605632   -> total 66156032 floats (~265 MB)

  k_ln_stats<<<384, 192, 0, stream>>>(x1, x2, mu, rstd);
  k_transpose_w<<<576, 256, 0, stream>>>(qkvw, wT);
  k_qkv_gemm<<<1152 * 9, 256, 0, stream>>>(x1, x2, mu, rstd, lnw, lnb, wT, qkv);
  k_attn_stats<<<2 * BHN * 81, 256, 0, stream>>>(qkv, rs_part, cs_part);
  k_stats_reduce<<<(2 * BHN * NSEQ + 255) / 256, 256, 0, stream>>>(rs_part, cs_part, rs, cs);
  k_apply_t<<<2 * BHN * 9, 256, 0, stream>>>(qkv, rs, cs, tbuf);
  k_f_gemm<<<2 * BHN, 256, 0, stream>>>(qkv, tbuf, featT);
  k_proj_partial<<<8 * 49, 512, 0, stream>>>(featT, pw, p);
  k_finalize<<<32768 / 256, 256, 0, stream>>>(p, pb, out);
}

// Round 2
// 1136.994 us; speedup vs baseline: 1.8845x; 1.8845x over previous
//
#include <hip/hip_runtime.h>

#define NSEQ 576
#define CDIM 256
#define HEADS 3
#define HD 64
#define FEAT 192      // HEADS*HD
#define QKVF 576      // 3*FEAT
#define VP 70         // HD+6
#define BHN 192       // 64*3
#define DIMSZ 29400   // 2*3*70*70

typedef __attribute__((ext_vector_type(8))) _Float16 half8;
typedef __attribute__((ext_vector_type(4))) _Float16 half4;
typedef __attribute__((ext_vector_type(4))) float f32x4;

#define MFMA16(A,B,C) __builtin_amdgcn_mfma_f32_16x16x32_f16(A,B,C,0,0,0)

// ---- positional encoding: pos[n] = {py^2, px^2, py*px, py, px, 1},
//      py = ys[n%24], px = xs[n/24], linspace(-1,1,24)
__device__ __forceinline__ float posval(int n, int pe){
  int yi = n % 24, xi = n / 24;
  float py = (float)yi * (2.0f/23.0f) - 1.0f;
  float px = (float)xi * (2.0f/23.0f) - 1.0f;
  switch(pe){
    case 0: return py*py;
    case 1: return px*px;
    case 2: return py*px;
    case 3: return py;
    case 4: return px;
    default: return 1.0f;
  }
}

// Stage a 64x64 fp32 tile (row stride ldsrc) into split-f16 LDS arrays, stride 72.
// 256 threads: row = t>>2, 16 consecutive d per (t&3) quarter -> coalesced 64B/4-lane.
__device__ __forceinline__ void stage_tile_split(const float* __restrict__ src, int ldsrc,
                                                 _Float16 (*sh)[72], _Float16 (*sl)[72], int t){
  int row = t >> 2, c = t & 3;
  const float* p = src + (size_t)row * ldsrc + c * 16;
  #pragma unroll
  for (int rr = 0; rr < 4; ++rr){
    float4 v = *(const float4*)(p + rr * 4);
    half4 h, l;
    h.x = (_Float16)v.x; l.x = (_Float16)(v.x - (float)h.x);
    h.y = (_Float16)v.y; l.y = (_Float16)(v.y - (float)h.y);
    h.z = (_Float16)v.z; l.z = (_Float16)(v.z - (float)h.z);
    h.w = (_Float16)v.w; l.w = (_Float16)(v.w - (float)h.w);
    *(half4*)&sh[row][c*16 + rr*4] = h;
    *(half4*)&sl[row][c*16 + rr*4] = l;
  }
}

// Build a half8 MFMA fragment: element i = s[row][dbase + (i>>2)*16 + (i&3)].
// k-enumeration d(hi,i) = dbase(hi) + (i>>2)*16 + (i&3) used IDENTICALLY for A and B
// operands -> result invariant to the hardware's internal k permutation.
__device__ __forceinline__ half8 frag_from(const _Float16 (*s)[72], int row, int dbase){
  half4 a = *(const half4*)&s[row][dbase];
  half4 b = *(const half4*)&s[row][dbase + 16];
  return __builtin_shufflevector(a, b, 0, 1, 2, 3, 4, 5, 6, 7);
}

// ---- K0: LayerNorm stats (mu, rstd) per (input, b, n)
__global__ __launch_bounds__(192) void k_ln_stats(const float* __restrict__ x1, const float* __restrict__ x2,
                                                  float* __restrict__ mu, float* __restrict__ rstd){
  int idx = blockIdx.x;                 // 2*64*3 = 384
  int i2 = idx / 192;
  int rem = idx % 192;
  int b = rem / 3, ng = rem % 3;
  int n = ng * 192 + threadIdx.x;
  const float* x = i2 ? x2 : x1;
  const float* xb = x + (size_t)b * CDIM * NSEQ + n;
  float s = 0.f, sq = 0.f;
  for (int c = 0; c < CDIM; ++c){
    float v = xb[(size_t)c * NSEQ];
    s += v; sq += v * v;
  }
  float m = s * (1.0f/256.0f);
  float var = sq * (1.0f/256.0f) - m * m;
  int o = (i2 * 64 + b) * NSEQ + n;
  mu[o] = m;
  rstd[o] = rsqrtf(var + 1e-5f);
}

// ---- K0b: transpose qkv_w [576,256] -> wT [256,576]
__global__ __launch_bounds__(256) void k_transpose_w(const float* __restrict__ w, float* __restrict__ wT){
  int f = blockIdx.x;        // 576
  int c = threadIdx.x;       // 256
  wT[(size_t)c * QKVF + f] = w[(size_t)f * CDIM + c];
}

// ---- K1: fused LN + QKV GEMM (fp32; MFMA conversion next round)
__global__ __launch_bounds__(256) void k_qkv_gemm(const float* __restrict__ x1, const float* __restrict__ x2,
                                                  const float* __restrict__ mu, const float* __restrict__ rstd,
                                                  const float* __restrict__ lnw, const float* __restrict__ lnb,
                                                  const float* __restrict__ wT, float* __restrict__ qkv){
  int wg = blockIdx.x;               // 1152*9
  int ft = wg % 9;
  int mt = wg / 9;
  int ibn = mt * 64;
  int i2 = ibn / (64 * NSEQ);
  int bn = ibn % (64 * NSEQ);
  int b  = bn / NSEQ;
  int n0 = bn % NSEQ;
  const float* x = i2 ? x2 : x1;
  const float* xb = x + (size_t)b * CDIM * NSEQ + n0;
  __shared__ __align__(16) float As[16][72];
  __shared__ __align__(16) float Bs[16][72];
  __shared__ float smu[64], srstd[64];
  int t = threadIdx.x, tx = t & 15, ty = t >> 4;
  if (t < 64){ smu[t] = mu[ibn + t]; srstd[t] = rstd[ibn + t]; }
  float acc[4][4] = {};
  for (int k0 = 0; k0 < CDIM; k0 += 16){
    __syncthreads();
    #pragma unroll
    for (int r = 0; r < 4; ++r){
      int l = t + 256 * r;
      int m = l & 63, k = l >> 6;
      float v = xb[(size_t)(k0 + k) * NSEQ + m];
      As[k][m] = (v - smu[m]) * srstd[m] * lnw[k0 + k] + lnb[k0 + k];
      Bs[k][m] = wT[(size_t)(k0 + k) * QKVF + ft * 64 + m];
    }
    __syncthreads();
    #pragma unroll
    for (int k = 0; k < 16; ++k){
      float4 a4 = *(const float4*)&As[k][ty * 4];
      float4 b4 = *(const float4*)&Bs[k][tx * 4];
      float aa[4] = {a4.x, a4.y, a4.z, a4.w};
      float bb[4] = {b4.x, b4.y, b4.z, b4.w};
      #pragma unroll
      for (int i = 0; i < 4; ++i)
        #pragma unroll
        for (int j = 0; j < 4; ++j)
          acc[i][j] += aa[i] * bb[j];
    }
  }
  #pragma unroll
  for (int i = 0; i < 4; ++i){
    float4 st = make_float4(acc[i][0], acc[i][1], acc[i][2], acc[i][3]);
    *(float4*)&qkv[(size_t)(ibn + ty * 4 + i) * QKVF + ft * 64 + tx * 4] = st;
  }
}

// ---- K2: attention stats via MFMA f16-split. Block = (map,bh,nt): 64 n-rows, all m.
// Computes S^T = mfma(K,Q) tiles, e = exp(0.125*dot); full row sums -> rs (direct),
// per-nt partial col sums -> cs_part.
__global__ __launch_bounds__(256) void k_attn_stats_mfma(const float* __restrict__ qkv,
                                                         float* __restrict__ rs, float* __restrict__ cs_part){
  int wg = (blockIdx.x & 7) * 432 + (blockIdx.x >> 3);   // XCD-chunk swizzle, 3456=8*432
  int map = wg / (BHN * 9);
  int r   = wg % (BHN * 9);
  int bh = r / 9, nt = r % 9;
  int b = bh / 3, h = bh % 3;
  int qi = 1 - map, ki = map;
  int mb = map * BHN + bh;
  const float* qb = qkv + (size_t)(qi * 64 + b) * NSEQ * QKVF + h * HD;
  const float* kb = qkv + (size_t)(ki * 64 + b) * NSEQ * QKVF + FEAT + h * HD;
  int n0 = nt * 64;
  __shared__ __align__(16) _Float16 Ash[64][72];
  __shared__ __align__(16) _Float16 Asl[64][72];
  __shared__ float cpart[4][64];
  int t = threadIdx.x;
  int w = t >> 6, lane = t & 63, tx = lane & 15, hi = lane >> 4;

  // stage Q rows n0..n0+63, build per-wave persistent Q B-frags (B col = lane&15 = n)
  stage_tile_split(qb + (size_t)n0 * QKVF, QKVF, Ash, Asl, t);
  __syncthreads();
  half8 qh0 = frag_from(Ash, w * 16 + tx, 0 + hi * 4);
  half8 qh1 = frag_from(Ash, w * 16 + tx, 32 + hi * 4);
  half8 ql0 = frag_from(Asl, w * 16 + tx, 0 + hi * 4);
  half8 ql1 = frag_from(Asl, w * 16 + tx, 32 + hi * 4);

  float rsum = 0.f;
  for (int mt = 0; mt < 9; ++mt){
    int m0 = mt * 64;
    __syncthreads();
    stage_tile_split(kb + (size_t)m0 * QKVF, QKVF, Ash, Asl, t);
    __syncthreads();
    f32x4 acc[4];
    #pragma unroll
    for (int s = 0; s < 4; ++s) acc[s] = (f32x4){0.f, 0.f, 0.f, 0.f};
    #pragma unroll
    for (int s = 0; s < 4; ++s){
      half8 kh0 = frag_from(Ash, s * 16 + tx, 0 + hi * 4);
      half8 kl0 = frag_from(Asl, s * 16 + tx, 0 + hi * 4);
      half8 kh1 = frag_from(Ash, s * 16 + tx, 32 + hi * 4);
      half8 kl1 = frag_from(Asl, s * 16 + tx, 32 + hi * 4);
      acc[s] = MFMA16(kh0, qh0, acc[s]);
      acc[s] = MFMA16(kl0, qh0, acc[s]);
      acc[s] = MFMA16(kh0, ql0, acc[s]);
      acc[s] = MFMA16(kh1, qh1, acc[s]);
      acc[s] = MFMA16(kl1, qh1, acc[s]);
      acc[s] = MFMA16(kh1, ql1, acc[s]);
    }
    // lane (tx,hi), acc[s][r] = dot for (m = m0+s*16+hi*4+r, n = n0+w*16+tx)
    #pragma unroll
    for (int s = 0; s < 4; ++s){
      #pragma unroll
      for (int rr = 0; rr < 4; ++rr){
        float e = __expf(acc[s][rr] * 0.125f);
        rsum += e;
        float c = e;
        c += __shfl_xor(c, 1);
        c += __shfl_xor(c, 2);
        c += __shfl_xor(c, 4);
        c += __shfl_xor(c, 8);
        if (tx == 0) cpart[w][s * 16 + hi * 4 + rr] = c;
      }
    }
    __syncthreads();
    if (t < 64){
      float s2 = cpart[0][t] + cpart[1][t] + cpart[2][t] + cpart[3][t];
      cs_part[((size_t)mb * 9 + nt) * NSEQ + m0 + t] = s2;
    }
  }
  // full row sums: reduce across hi groups (lanes tx, tx+16, tx+32, tx+48)
  rsum += __shfl_xor(rsum, 16);
  rsum += __shfl_xor(rsum, 32);
  if (lane < 16) rs[(size_t)mb * NSEQ + n0 + w * 16 + lane] = rsum;
}

// ---- K2b: reduce 9 col-sum partials -> cs
__global__ __launch_bounds__(256) void k_cs_reduce(const float* __restrict__ cs_part, float* __restrict__ cs){
  int tid = blockIdx.x * 256 + threadIdx.x;
  if (tid >= 2 * BHN * NSEQ) return;
  int mb = tid / NSEQ, m = tid % NSEQ;
  float s = 0.f;
  #pragma unroll
  for (int p = 0; p < 9; ++p)
    s += cs_part[((size_t)mb * 9 + p) * NSEQ + m];
  cs[tid] = s;
}

// ---- K3: apply pass via MFMA. Per (map,bh,nt): recompute S^T tiles, af = exp(0.25*dot)
// * rinv[n] * cinv[m]; af re-packed in-register as PV B-operand; A = vp^T from LDS;
// t^T accumulated in MFMA -> tbuf[mb][n][e].
__global__ __launch_bounds__(256) void k_apply_mfma(const float* __restrict__ qkv,
                                                    const float* __restrict__ rs, const float* __restrict__ cs,
                                                    float* __restrict__ tbuf){
  int wg = (blockIdx.x & 7) * 432 + (blockIdx.x >> 3);   // XCD-chunk swizzle
  int map = wg / (BHN * 9);
  int r   = wg % (BHN * 9);
  int bh = r / 9, nt = r % 9;
  int b = bh / 3, h = bh % 3;
  int qi = 1 - map, ki = map, vi = map;
  int mb = map * BHN + bh;
  const float* qb = qkv + (size_t)(qi * 64 + b) * NSEQ * QKVF + h * HD;
  const float* kb = qkv + (size_t)(ki * 64 + b) * NSEQ * QKVF + FEAT + h * HD;
  const float* vb = qkv + (size_t)(vi * 64 + b) * NSEQ * QKVF + 2 * FEAT + h * HD;
  int n0 = nt * 64;
  __shared__ __align__(16) _Float16 Ash[64][72];
  __shared__ __align__(16) _Float16 Asl[64][72];
  __shared__ __align__(16) _Float16 Vth[80][72];   // vp^T: rows e (70 + zero pad), cols m
  __shared__ __align__(16) _Float16 Vtl[80][72];
  __shared__ float cinv[64];
  int t = threadIdx.x;
  int w = t >> 6, lane = t & 63, tx = lane & 15, hi = lane >> 4;

  // zero pad rows e = 70..79 once
  for (int i = t; i < 640; i += 256){
    int e = 70 + (i >> 6), m = i & 63;
    Vth[e][m] = (_Float16)0.f;
    Vtl[e][m] = (_Float16)0.f;
  }
  // stage Q, build persistent B-frags
  stage_tile_split(qb + (size_t)n0 * QKVF, QKVF, Ash, Asl, t);
  __syncthreads();
  half8 qh0 = frag_from(Ash, w * 16 + tx, 0 + hi * 4);
  half8 qh1 = frag_from(Ash, w * 16 + tx, 32 + hi * 4);
  half8 ql0 = frag_from(Asl, w * 16 + tx, 0 + hi * 4);
  half8 ql1 = frag_from(Asl, w * 16 + tx, 32 + hi * 4);
  float rinv = 1.0f / rs[(size_t)mb * NSEQ + n0 + w * 16 + tx];

  f32x4 tacc[5];
  #pragma unroll
  for (int et = 0; et < 5; ++et) tacc[et] = (f32x4){0.f, 0.f, 0.f, 0.f};

  for (int mt = 0; mt < 9; ++mt){
    int m0 = mt * 64;
    __syncthreads();
    stage_tile_split(kb + (size_t)m0 * QKVF, QKVF, Ash, Asl, t);
    {
      // stage vp^T tile: v columns transposed + positional rows, split f16
      int m = t >> 2, c = t & 3;
      const float* p = vb + (size_t)(m0 + m) * QKVF + c * 16;
      #pragma unroll
      for (int rr = 0; rr < 4; ++rr){
        float4 v = *(const float4*)(p + rr * 4);
        int e = c * 16 + rr * 4;
        float vv[4] = {v.x, v.y, v.z, v.w};
        #pragma unroll
        for (int j = 0; j < 4; ++j){
          _Float16 hh = (_Float16)vv[j];
          Vth[e + j][m] = hh;
          Vtl[e + j][m] = (_Float16)(vv[j] - (float)hh);
        }
      }
      if (t < 64){
        int mg = m0 + t;
        int yi = mg % 24, xi = mg / 24;
        float py = (float)yi * (2.0f/23.0f) - 1.0f;
        float px = (float)xi * (2.0f/23.0f) - 1.0f;
        float pv[6] = {py*py, px*px, py*px, py, px, 1.0f};
        #pragma unroll
        for (int pe = 0; pe < 6; ++pe){
          _Float16 hh = (_Float16)pv[pe];
          Vth[64 + pe][t] = hh;
          Vtl[64 + pe][t] = (_Float16)(pv[pe] - (float)hh);
        }
        cinv[t] = 1.0f / cs[(size_t)mb * NSEQ + m0 + t];
      }
    }
    __syncthreads();

    // S^T tiles
    f32x4 acc[4];
    #pragma unroll
    for (int s = 0; s < 4; ++s) acc[s] = (f32x4){0.f, 0.f, 0.f, 0.f};
    #pragma unroll
    for (int s = 0; s < 4; ++s){
      half8 kh0 = frag_from(Ash, s * 16 + tx, 0 + hi * 4);
      half8 kl0 = frag_from(Asl, s * 16 + tx, 0 + hi * 4);
      half8 kh1 = frag_from(Ash, s * 16 + tx, 32 + hi * 4);
      half8 kl1 = frag_from(Asl, s * 16 + tx, 32 + hi * 4);
      acc[s] = MFMA16(kh0, qh0, acc[s]);
      acc[s] = MFMA16(kl0, qh0, acc[s]);
      acc[s] = MFMA16(kh0, ql0, acc[s]);
      acc[s] = MFMA16(kh1, qh1, acc[s]);
      acc[s] = MFMA16(kl1, qh1, acc[s]);
      acc[s] = MFMA16(kh1, ql1, acc[s]);
    }
    // af + split; re-pack as PV B-operand: element i of chunk mc corresponds to
    // m = m0 + mc*32 + (i>>2)*16 + hi*4 + (i&3)  (same enumeration as A below)
    half8 bhf[2], blf[2];
    #pragma unroll
    for (int s = 0; s < 4; ++s){
      #pragma unroll
      for (int rr = 0; rr < 4; ++rr){
        float e2 = __expf(acc[s][rr] * 0.25f);
        float af = e2 * rinv * cinv[s * 16 + hi * 4 + rr];
        _Float16 hh = (_Float16)af;
        _Float16 ll = (_Float16)(af - (float)hh);
        bhf[s >> 1][(s & 1) * 4 + rr] = hh;
        blf[s >> 1][(s & 1) * 4 + rr] = ll;
      }
    }
    // PV: t^T[e][n] += sum_m vp[m][e] * af[m][n]
    #pragma unroll
    for (int et = 0; et < 5; ++et){
      #pragma unroll
      for (int mc = 0; mc < 2; ++mc){
        half8 vhf = frag_from(Vth, et * 16 + tx, mc * 32 + hi * 4);
        half8 vlf = frag_from(Vtl, et * 16 + tx, mc * 32 + hi * 4);
        tacc[et] = MFMA16(vhf, bhf[mc], tacc[et]);
        tacc[et] = MFMA16(vhf, blf[mc], tacc[et]);
        tacc[et] = MFMA16(vlf, bhf[mc], tacc[et]);
      }
    }
  }
  // write out: lane holds t^T[e = et*16+hi*4+rr][n = n0+w*16+tx]
  #pragma unroll
  for (int et = 0; et < 5; ++et){
    #pragma unroll
    for (int rr = 0; rr < 4; ++rr){
      int e = et * 16 + hi * 4 + rr;
      if (e < VP)
        tbuf[((size_t)mb * NSEQ + n0 + w * 16 + tx) * VP + e] = tacc[et][rr];
    }
  }
}

// ---- K4: f[d][e] = sum_n vp[n][d] * t[n][e] per (map,bh); write featT[k][b]
__global__ __launch_bounds__(256) void k_f_gemm(const float* __restrict__ qkv, const float* __restrict__ tbuf,
                                                float* __restrict__ featT){
  int wg = blockIdx.x;                 // 384
  int map = wg / BHN, bh = wg % BHN;
  int b = bh / 3, h = bh % 3;
  const float* vb = qkv + (size_t)(map * 64 + b) * NSEQ * QKVF + 2 * FEAT + h * HD;
  int mb = wg;
  __shared__ float Vs[64][72];
  __shared__ float Ts[64][72];
  int t = threadIdx.x, tx = t & 15, ty = t >> 4;
  int drow[5], ecol[5];
  #pragma unroll
  for (int u = 0; u < 5; ++u){
    int d = ty + 16 * u; drow[u] = (d < VP) ? d : 0;
    int e = tx + 16 * u; ecol[u] = (e < VP) ? e : 0;
  }
  float acc[5][5] = {};
  for (int c0 = 0; c0 < NSEQ; c0 += 64){
    __syncthreads();
    #pragma unroll
    for (int rr = 0; rr < 16; ++rr){
      int nn = (t >> 6) + rr * 4;
      int e = t & 63;
      Vs[nn][e] = vb[(size_t)(c0 + nn) * QKVF + e];
    }
    #pragma unroll
    for (int rr = 0; rr < 2; ++rr){
      int idx = t + 256 * rr;
      int nn = idx & 63, pe = idx >> 6;
      Vs[nn][64 + pe] = (pe < 6) ? posval(c0 + nn, pe) : 0.0f;
    }
    for (int idx = t; idx < 64 * VP; idx += 256){
      int nn = idx / VP, e = idx % VP;
      Ts[nn][e] = tbuf[((size_t)mb * NSEQ + c0 + nn) * VP + e];
    }
    __syncthreads();
    for (int n = 0; n < 64; ++n){
      float vd[5], te[5];
      #pragma unroll
      for (int u = 0; u < 5; ++u) vd[u] = Vs[n][drow[u]];
      #pragma unroll
      for (int u = 0; u < 5; ++u) te[u] = Ts[n][ecol[u]];
      #pragma unroll
      for (int u = 0; u < 5; ++u)
        #pragma unroll
        for (int v2 = 0; v2 < 5; ++v2)
          acc[u][v2] += vd[u] * te[v2];
    }
  }
  #pragma unroll
  for (int u = 0; u < 5; ++u)
    #pragma unroll
    for (int v2 = 0; v2 < 5; ++v2){
      int d = ty + 16 * u, e = tx + 16 * v2;
      if (d < VP && e < VP)
        featT[(size_t)(map * 14700 + h * 4900 + d * VP + e) * 64 + b] = acc[u][v2];
    }
}

// ---- K5: projection partials
__global__ __launch_bounds__(512) void k_proj_partial(const float* __restrict__ featT, const float* __restrict__ pw,
                                                      float* __restrict__ p){
  int ot = blockIdx.x & 7;
  int s  = blockIdx.x >> 3;            // 0..48
  int t = threadIdx.x;
  int b = t & 63, og = t >> 6;         // og 0..7
  int obase = ot * 64 + og * 8;
  float acc[8] = {};
  int k0 = s * 600;
  for (int k = k0; k < k0 + 600; ++k){
    float fv = featT[(size_t)k * 64 + b];
    #pragma unroll
    for (int jj = 0; jj < 8; ++jj)
      acc[jj] += fv * pw[(size_t)(obase + jj) * DIMSZ + k];
  }
  #pragma unroll
  for (int jj = 0; jj < 8; ++jj)
    p[(size_t)s * 32768 + (size_t)(obase + jj) * 64 + b] = acc[jj];
}

// ---- K6: finalize
__global__ __launch_bounds__(256) void k_finalize(const float* __restrict__ p, const float* __restrict__ pb,
                                                  float* __restrict__ out){
  int gid = blockIdx.x * 256 + threadIdx.x;   // 32768 = b*512 + o
  int o = gid & 511, b = gid >> 9;
  float s = pb[o];
  #pragma unroll
  for (int s2 = 0; s2 < 49; ++s2)
    s += p[(size_t)s2 * 32768 + (size_t)o * 64 + b];
  out[gid] = fmaxf(s, 0.0f);
}

extern "C" void kernel_launch(void* const* d_in, const int* in_sizes, int n_in,
                              void* d_out, int out_size, void* d_ws, size_t ws_size,
                              hipStream_t stream) {
  const float* x1   = (const float*)d_in[0];
  const float* x2   = (const float*)d_in[1];
  const float* lnw  = (const float*)d_in[2];
  const float* lnb  = (const float*)d_in[3];
  const float* qkvw = (const float*)d_in[4];
  const float* pw   = (const float*)d_in[5];
  const float* pb   = (const float*)d_in[6];
  float* out = (float*)d_out;

  float* w = (float*)d_ws;
  float* mu      = w;                    // 73728
  float* rstd    = w + 73728;            // 73728
  float* wT      = w + 147456;           // 147456
  float* qkv     = w + 294912;           // 42467328
  float* cs_part = w + 42762240;         // 1990656
  float* rs      = w + 44752896;         // 221184
  float* cs      = w + 44974080;         // 221184
  float* tbuf    = w + 45195264;         // 15482880
  float* featT   = w + 60678144;         // 1881600
  float* p       = w + 62559744;         // 1605632  -> total 64165376 floats (~257 MB)

  k_ln_stats<<<384, 192, 0, stream>>>(x1, x2, mu, rstd);
  k_transpose_w<<<576, 256, 0, stream>>>(qkvw, wT);
  k_qkv_gemm<<<1152 * 9, 256, 0, stream>>>(x1, x2, mu, rstd, lnw, lnb, wT, qkv);
  k_attn_stats_mfma<<<2 * BHN * 9, 256, 0, stream>>>(qkv, rs, cs_part);
  k_cs_reduce<<<(2 * BHN * NSEQ + 255) / 256, 256, 0, stream>>>(cs_part, cs);
  k_apply_mfma<<<2 * BHN * 9, 256, 0, stream>>>(qkv, rs, cs, tbuf);
  k_f_gemm<<<2 * BHN, 256, 0, stream>>>(qkv, tbuf, featT);
  k_proj_partial<<<8 * 49, 512, 0, stream>>>(featT, pw, p);
  k_finalize<<<32768 / 256, 256, 0, stream>>>(p, pb, out);
}

// Round 3
// 1017.524 us; speedup vs baseline: 2.1058x; 1.1174x over previous
//
#include <hip/hip_runtime.h>

#define NSEQ 576
#define CDIM 256
#define HEADS 3
#define HD 64
#define FEAT 192      // HEADS*HD
#define QKVF 576      // 3*FEAT
#define QK_F 384      // stored q,k cols
#define VP 70         // HD+6
#define BHN 192       // 64*3
#define DIMSZ 29400   // 2*3*70*70

typedef __attribute__((ext_vector_type(8))) _Float16 half8;
typedef __attribute__((ext_vector_type(4))) _Float16 half4;
typedef __attribute__((ext_vector_type(4))) float f32x4;

#define MFMA16(A,B,C) __builtin_amdgcn_mfma_f32_16x16x32_f16(A,B,C,0,0,0)

// positional encoding: pos[n] = {py^2, px^2, py*px, py, px, 1}
__device__ __forceinline__ float posval(int n, int pe){
  int yi = n % 24, xi = n / 24;
  float py = (float)yi * (2.0f/23.0f) - 1.0f;
  float px = (float)xi * (2.0f/23.0f) - 1.0f;
  switch(pe){
    case 0: return py*py;
    case 1: return px*px;
    case 2: return py*px;
    case 3: return py;
    case 4: return px;
    default: return 1.0f;
  }
}

// MFMA fragment with k-enum kappa(hi,i) = dbase + (i>>2)*16 + (i&3); LD = LDS row stride
template<int LD>
__device__ __forceinline__ half8 fragT(const _Float16 (*s)[LD], int row, int dbase){
  half4 a = *(const half4*)&s[row][dbase];
  half4 b = *(const half4*)&s[row][dbase + 16];
  return __builtin_shufflevector(a, b, 0, 1, 2, 3, 4, 5, 6, 7);
}

// copy 64 rows x 64 cols of f16 from global (row stride rstr halfs) into LDS [64][72]
__device__ __forceinline__ void stage_copy64(const _Float16* __restrict__ src, int rstr,
                                             _Float16 (*d)[72], int t){
  #pragma unroll
  for (int k2 = 0; k2 < 2; ++k2){
    int idx = t + 256 * k2;               // 512 chunks of 8 halfs
    int row = idx >> 3, c = (idx & 7) << 3;
    half8 v = *(const half8*)(src + (size_t)row * rstr + c);
    *(half4*)&d[row][c]     = (half4){v[0], v[1], v[2], v[3]};
    *(half4*)&d[row][c + 4] = (half4){v[4], v[5], v[6], v[7]};
  }
}

// ---- K0: LayerNorm stats
__global__ __launch_bounds__(192) void k_ln_stats(const float* __restrict__ x1, const float* __restrict__ x2,
                                                  float* __restrict__ mu, float* __restrict__ rstd){
  int idx = blockIdx.x;                 // 384
  int i2 = idx / 192;
  int rem = idx % 192;
  int b = rem / 3, ng = rem % 3;
  int n = ng * 192 + threadIdx.x;
  const float* x = i2 ? x2 : x1;
  const float* xb = x + (size_t)b * CDIM * NSEQ + n;
  float s = 0.f, sq = 0.f;
  for (int c = 0; c < CDIM; ++c){
    float v = xb[(size_t)c * NSEQ];
    s += v; sq += v * v;
  }
  float m = s * (1.0f/256.0f);
  float var = sq * (1.0f/256.0f) - m * m;
  int o = (i2 * 64 + b) * NSEQ + n;
  mu[o] = m;
  rstd[o] = rsqrtf(var + 1e-5f);
}

// ---- K1: fused LN + QKV GEMM via MFMA split-f16. Block = 64 rows x 64 f.
// q/k blocks -> qh/ql [row][384]; v blocks -> transposed into vpTh/l[mb][d][n].
__global__ __launch_bounds__(256) void k_qkv_gemm_mfma(const float* __restrict__ x1, const float* __restrict__ x2,
                                                       const float* __restrict__ mu, const float* __restrict__ rstd,
                                                       const float* __restrict__ lnw, const float* __restrict__ lnb,
                                                       const float* __restrict__ qkvw,
                                                       _Float16* __restrict__ qh, _Float16* __restrict__ ql,
                                                       _Float16* __restrict__ vpTh, _Float16* __restrict__ vpTl){
  int wg = (blockIdx.x & 7) * 1296 + (blockIdx.x >> 3);   // 10368 = 8*1296
  int ft = wg % 9;
  int mt = wg / 9;
  int ibn = mt * 64;
  int i2 = ibn / (64 * NSEQ);
  int bn = ibn % (64 * NSEQ);
  int b  = bn / NSEQ;
  int n0 = bn % NSEQ;
  const float* x = i2 ? x2 : x1;
  const float* xb = x + (size_t)b * CDIM * NSEQ + n0;
  __shared__ __align__(16) _Float16 Xh[64][68];
  __shared__ __align__(16) _Float16 Xl[64][68];
  __shared__ __align__(16) _Float16 Wh[64][68];
  __shared__ __align__(16) _Float16 Wl[64][68];
  __shared__ float smu[64], srstd[64], slnw[256], slnb[256];
  int t = threadIdx.x;
  int w = t >> 6, lane = t & 63, tx = lane & 15, hi = lane >> 4;
  if (t < 64){ smu[t] = mu[ibn + t]; srstd[t] = rstd[ibn + t]; }
  slnw[t] = lnw[t]; slnb[t] = lnb[t];

  f32x4 acc[4];
  #pragma unroll
  for (int s = 0; s < 4; ++s) acc[s] = (f32x4){0.f, 0.f, 0.f, 0.f};

  int nA = t & 63, cg = t >> 6;
  int fr = t >> 2, cq = t & 3;
  for (int c0 = 0; c0 < CDIM; c0 += 64){
    __syncthreads();
    // stage X transposed + LN + split
    float mun = smu[nA], rsn = srstd[nA];
    #pragma unroll
    for (int rr = 0; rr < 16; ++rr){
      int c = cg * 16 + rr;
      float v = xb[(size_t)(c0 + c) * NSEQ + nA];
      float xv = (v - mun) * rsn * slnw[c0 + c] + slnb[c0 + c];
      _Float16 hh = (_Float16)xv;
      Xh[nA][c] = hh;
      Xl[nA][c] = (_Float16)(xv - (float)hh);
    }
    // stage W rows f, split
    const float* wp = qkvw + (size_t)(ft * 64 + fr) * CDIM + c0 + cq * 16;
    #pragma unroll
    for (int rr = 0; rr < 4; ++rr){
      float4 wv = *(const float4*)(wp + rr * 4);
      half4 h, l;
      h.x = (_Float16)wv.x; l.x = (_Float16)(wv.x - (float)h.x);
      h.y = (_Float16)wv.y; l.y = (_Float16)(wv.y - (float)h.y);
      h.z = (_Float16)wv.z; l.z = (_Float16)(wv.z - (float)h.z);
      h.w = (_Float16)wv.w; l.w = (_Float16)(wv.w - (float)h.w);
      *(half4*)&Wh[fr][cq * 16 + rr * 4] = h;
      *(half4*)&Wl[fr][cq * 16 + rr * 4] = l;
    }
    __syncthreads();
    #pragma unroll
    for (int kc = 0; kc < 2; ++kc){
      half8 wh = fragT<68>(Wh, w * 16 + tx, kc * 32 + hi * 4);
      half8 wl = fragT<68>(Wl, w * 16 + tx, kc * 32 + hi * 4);
      #pragma unroll
      for (int s = 0; s < 4; ++s){
        half8 xh = fragT<68>(Xh, s * 16 + tx, kc * 32 + hi * 4);
        half8 xl = fragT<68>(Xl, s * 16 + tx, kc * 32 + hi * 4);
        acc[s] = MFMA16(xh, wh, acc[s]);
        acc[s] = MFMA16(xl, wh, acc[s]);
        acc[s] = MFMA16(xh, wl, acc[s]);
      }
    }
  }
  // epilogue: lane (tx,hi) acc[s][rr] = out[row = s*16+hi*4+rr][f = w*16+tx]
  if (ft < 6){
    #pragma unroll
    for (int s = 0; s < 4; ++s)
      #pragma unroll
      for (int rr = 0; rr < 4; ++rr){
        float v = acc[s][rr];
        _Float16 hh = (_Float16)v;
        size_t o = (size_t)(ibn + s * 16 + hi * 4 + rr) * QK_F + ft * 64 + w * 16 + tx;
        qh[o] = hh;
        ql[o] = (_Float16)(v - (float)hh);
      }
  } else {
    __syncthreads();
    #pragma unroll
    for (int s = 0; s < 4; ++s)
      #pragma unroll
      for (int rr = 0; rr < 4; ++rr){
        float v = acc[s][rr];
        _Float16 hh = (_Float16)v;
        Xh[s * 16 + hi * 4 + rr][w * 16 + tx] = hh;
        Xl[s * 16 + hi * 4 + rr][w * 16 + tx] = (_Float16)(v - (float)hh);
      }
    __syncthreads();
    int mbg = i2 * 192 + b * 3 + (ft - 6);
    #pragma unroll
    for (int it = 0; it < 16; ++it){
      int d = (t >> 6) + it * 4;
      int n2 = t & 63;
      size_t o = ((size_t)mbg * 80 + d) * NSEQ + n0 + n2;
      vpTh[o] = Xh[n2][d];
      vpTl[o] = Xl[n2][d];
    }
  }
}

// ---- K1b: fill vpT positional rows 64..79 (rows 70..79 zero)
__global__ __launch_bounds__(256) void k_pos_fill(_Float16* __restrict__ vpTh, _Float16* __restrict__ vpTl){
  int idx = blockIdx.x * 256 + threadIdx.x;   // 384*16*576
  if (idx >= 384 * 16 * NSEQ) return;
  int n = idx % NSEQ;
  int r = idx / NSEQ;
  int row = 64 + (r & 15);
  int mb = r >> 4;
  float v = 0.f;
  int pe = row - 64;
  if (pe < 6) v = posval(n, pe);
  _Float16 hh = (_Float16)v;
  size_t o = ((size_t)mb * 80 + row) * NSEQ + n;
  vpTh[o] = hh;
  vpTl[o] = (_Float16)(v - (float)hh);
}

// ---- K2: attention stats via MFMA (copy-staged from qh/ql)
__global__ __launch_bounds__(256) void k_attn_stats_mfma(const _Float16* __restrict__ qh, const _Float16* __restrict__ ql,
                                                         float* __restrict__ rs, float* __restrict__ cs_part){
  int wg = (blockIdx.x & 7) * 432 + (blockIdx.x >> 3);   // 3456 = 8*432
  int map = wg / (BHN * 9);
  int r   = wg % (BHN * 9);
  int bh = r / 9, nt = r % 9;
  int b = bh / 3, h = bh % 3;
  int qi = 1 - map, ki = map;
  int mb = map * BHN + bh;
  const _Float16* qbh = qh + (size_t)((qi * 64 + b) * NSEQ) * QK_F + h * HD;
  const _Float16* qbl = ql + (size_t)((qi * 64 + b) * NSEQ) * QK_F + h * HD;
  const _Float16* kbh = qh + (size_t)((ki * 64 + b) * NSEQ) * QK_F + FEAT + h * HD;
  const _Float16* kbl = ql + (size_t)((ki * 64 + b) * NSEQ) * QK_F + FEAT + h * HD;
  int n0 = nt * 64;
  __shared__ __align__(16) _Float16 Ash[64][72];
  __shared__ __align__(16) _Float16 Asl[64][72];
  __shared__ float cpart[4][64];
  int t = threadIdx.x;
  int w = t >> 6, lane = t & 63, tx = lane & 15, hi = lane >> 4;

  stage_copy64(qbh + (size_t)n0 * QK_F, QK_F, Ash, t);
  stage_copy64(qbl + (size_t)n0 * QK_F, QK_F, Asl, t);
  __syncthreads();
  half8 qh0 = fragT<72>(Ash, w * 16 + tx, 0 + hi * 4);
  half8 qh1 = fragT<72>(Ash, w * 16 + tx, 32 + hi * 4);
  half8 ql0 = fragT<72>(Asl, w * 16 + tx, 0 + hi * 4);
  half8 ql1 = fragT<72>(Asl, w * 16 + tx, 32 + hi * 4);

  float rsum = 0.f;
  for (int mt = 0; mt < 9; ++mt){
    int m0 = mt * 64;
    __syncthreads();
    stage_copy64(kbh + (size_t)m0 * QK_F, QK_F, Ash, t);
    stage_copy64(kbl + (size_t)m0 * QK_F, QK_F, Asl, t);
    __syncthreads();
    f32x4 acc[4];
    #pragma unroll
    for (int s = 0; s < 4; ++s) acc[s] = (f32x4){0.f, 0.f, 0.f, 0.f};
    #pragma unroll
    for (int s = 0; s < 4; ++s){
      half8 kh0 = fragT<72>(Ash, s * 16 + tx, 0 + hi * 4);
      half8 kl0 = fragT<72>(Asl, s * 16 + tx, 0 + hi * 4);
      half8 kh1 = fragT<72>(Ash, s * 16 + tx, 32 + hi * 4);
      half8 kl1 = fragT<72>(Asl, s * 16 + tx, 32 + hi * 4);
      acc[s] = MFMA16(kh0, qh0, acc[s]);
      acc[s] = MFMA16(kl0, qh0, acc[s]);
      acc[s] = MFMA16(kh0, ql0, acc[s]);
      acc[s] = MFMA16(kh1, qh1, acc[s]);
      acc[s] = MFMA16(kl1, qh1, acc[s]);
      acc[s] = MFMA16(kh1, ql1, acc[s]);
    }
    #pragma unroll
    for (int s = 0; s < 4; ++s){
      #pragma unroll
      for (int rr = 0; rr < 4; ++rr){
        float e = __expf(acc[s][rr] * 0.125f);
        rsum += e;
        float c = e;
        c += __shfl_xor(c, 1);
        c += __shfl_xor(c, 2);
        c += __shfl_xor(c, 4);
        c += __shfl_xor(c, 8);
        if (tx == 0) cpart[w][s * 16 + hi * 4 + rr] = c;
      }
    }
    __syncthreads();
    if (t < 64){
      float s2 = cpart[0][t] + cpart[1][t] + cpart[2][t] + cpart[3][t];
      cs_part[((size_t)mb * 9 + nt) * NSEQ + m0 + t] = s2;
    }
  }
  rsum += __shfl_xor(rsum, 16);
  rsum += __shfl_xor(rsum, 32);
  if (lane < 16) rs[(size_t)mb * NSEQ + n0 + w * 16 + lane] = rsum;
}

// ---- K2b: reduce 9 col-sum partials -> cs
__global__ __launch_bounds__(256) void k_cs_reduce(const float* __restrict__ cs_part, float* __restrict__ cs){
  int tid = blockIdx.x * 256 + threadIdx.x;
  if (tid >= 2 * BHN * NSEQ) return;
  int mb = tid / NSEQ, m = tid % NSEQ;
  float s = 0.f;
  #pragma unroll
  for (int p = 0; p < 9; ++p)
    s += cs_part[((size_t)mb * 9 + p) * NSEQ + m];
  cs[tid] = s;
}

// ---- K3: apply pass via MFMA (per map). Writes t^T split-f16 [mbL][80][576].
__global__ __launch_bounds__(256) void k_apply_mfma(const _Float16* __restrict__ qh, const _Float16* __restrict__ ql,
                                                    const _Float16* __restrict__ vpTh, const _Float16* __restrict__ vpTl,
                                                    const float* __restrict__ rs, const float* __restrict__ cs,
                                                    _Float16* __restrict__ tTh, _Float16* __restrict__ tTl, int map){
  int wg = (blockIdx.x & 7) * 216 + (blockIdx.x >> 3);   // 1728 = 8*216
  int bh = wg / 9, nt = wg % 9;
  int b = bh / 3, h = bh % 3;
  int qi = 1 - map, ki = map;
  int mb = map * BHN + bh;
  const _Float16* qbh = qh + (size_t)((qi * 64 + b) * NSEQ) * QK_F + h * HD;
  const _Float16* qbl = ql + (size_t)((qi * 64 + b) * NSEQ) * QK_F + h * HD;
  const _Float16* kbh = qh + (size_t)((ki * 64 + b) * NSEQ) * QK_F + FEAT + h * HD;
  const _Float16* kbl = ql + (size_t)((ki * 64 + b) * NSEQ) * QK_F + FEAT + h * HD;
  const _Float16* vTh = vpTh + (size_t)mb * 80 * NSEQ;   // v of input 'map'
  const _Float16* vTl = vpTl + (size_t)mb * 80 * NSEQ;
  int n0 = nt * 64;
  __shared__ __align__(16) _Float16 Ash[64][72];
  __shared__ __align__(16) _Float16 Asl[64][72];
  __shared__ __align__(16) _Float16 Vth[80][72];
  __shared__ __align__(16) _Float16 Vtl[80][72];
  __shared__ float cinv[64];
  int t = threadIdx.x;
  int w = t >> 6, lane = t & 63, tx = lane & 15, hi = lane >> 4;

  stage_copy64(qbh + (size_t)n0 * QK_F, QK_F, Ash, t);
  stage_copy64(qbl + (size_t)n0 * QK_F, QK_F, Asl, t);
  __syncthreads();
  half8 qh0 = fragT<72>(Ash, w * 16 + tx, 0 + hi * 4);
  half8 qh1 = fragT<72>(Ash, w * 16 + tx, 32 + hi * 4);
  half8 ql0 = fragT<72>(Asl, w * 16 + tx, 0 + hi * 4);
  half8 ql1 = fragT<72>(Asl, w * 16 + tx, 32 + hi * 4);
  float rinv = 1.0f / rs[(size_t)mb * NSEQ + n0 + w * 16 + tx];

  f32x4 tacc[5];
  #pragma unroll
  for (int et = 0; et < 5; ++et) tacc[et] = (f32x4){0.f, 0.f, 0.f, 0.f};

  for (int mt = 0; mt < 9; ++mt){
    int m0 = mt * 64;
    __syncthreads();
    stage_copy64(kbh + (size_t)m0 * QK_F, QK_F, Ash, t);
    stage_copy64(kbl + (size_t)m0 * QK_F, QK_F, Asl, t);
    // stage vp^T tiles (80 rows x 64 m) by copy
    #pragma unroll
    for (int k2 = 0; k2 < 3; ++k2){
      int idx = t + 256 * k2;
      if (idx < 640){
        int row = idx >> 3, c = (idx & 7) << 3;
        half8 v1 = *(const half8*)(vTh + (size_t)row * NSEQ + m0 + c);
        *(half4*)&Vth[row][c]     = (half4){v1[0], v1[1], v1[2], v1[3]};
        *(half4*)&Vth[row][c + 4] = (half4){v1[4], v1[5], v1[6], v1[7]};
        half8 v2 = *(const half8*)(vTl + (size_t)row * NSEQ + m0 + c);
        *(half4*)&Vtl[row][c]     = (half4){v2[0], v2[1], v2[2], v2[3]};
        *(half4*)&Vtl[row][c + 4] = (half4){v2[4], v2[5], v2[6], v2[7]};
      }
    }
    if (t < 64) cinv[t] = 1.0f / cs[(size_t)mb * NSEQ + m0 + t];
    __syncthreads();

    f32x4 acc[4];
    #pragma unroll
    for (int s = 0; s < 4; ++s) acc[s] = (f32x4){0.f, 0.f, 0.f, 0.f};
    #pragma unroll
    for (int s = 0; s < 4; ++s){
      half8 kh0 = fragT<72>(Ash, s * 16 + tx, 0 + hi * 4);
      half8 kl0 = fragT<72>(Asl, s * 16 + tx, 0 + hi * 4);
      half8 kh1 = fragT<72>(Ash, s * 16 + tx, 32 + hi * 4);
      half8 kl1 = fragT<72>(Asl, s * 16 + tx, 32 + hi * 4);
      acc[s] = MFMA16(kh0, qh0, acc[s]);
      acc[s] = MFMA16(kl0, qh0, acc[s]);
      acc[s] = MFMA16(kh0, ql0, acc[s]);
      acc[s] = MFMA16(kh1, qh1, acc[s]);
      acc[s] = MFMA16(kl1, qh1, acc[s]);
      acc[s] = MFMA16(kh1, ql1, acc[s]);
    }
    // af + split; re-pack as PV B-operand (m-enum matches A frags below)
    half8 bhf[2], blf[2];
    #pragma unroll
    for (int s = 0; s < 4; ++s){
      #pragma unroll
      for (int rr = 0; rr < 4; ++rr){
        float e2 = __expf(acc[s][rr] * 0.25f);
        float af = e2 * rinv * cinv[s * 16 + hi * 4 + rr];
        _Float16 hh = (_Float16)af;
        _Float16 ll = (_Float16)(af - (float)hh);
        bhf[s >> 1][(s & 1) * 4 + rr] = hh;
        blf[s >> 1][(s & 1) * 4 + rr] = ll;
      }
    }
    #pragma unroll
    for (int et = 0; et < 5; ++et){
      #pragma unroll
      for (int mc = 0; mc < 2; ++mc){
        half8 vhf = fragT<72>(Vth, et * 16 + tx, mc * 32 + hi * 4);
        half8 vlf = fragT<72>(Vtl, et * 16 + tx, mc * 32 + hi * 4);
        tacc[et] = MFMA16(vhf, bhf[mc], tacc[et]);
        tacc[et] = MFMA16(vhf, blf[mc], tacc[et]);
        tacc[et] = MFMA16(vlf, bhf[mc], tacc[et]);
      }
    }
  }
  // write t^T split: lane holds t^T[e = et*16+hi*4+rr][n = n0+w*16+tx]
  #pragma unroll
  for (int et = 0; et < 5; ++et){
    #pragma unroll
    for (int rr = 0; rr < 4; ++rr){
      int e = et * 16 + hi * 4 + rr;
      float v = tacc[et][rr];
      _Float16 hh = (_Float16)v;
      size_t o = ((size_t)bh * 80 + e) * NSEQ + n0 + w * 16 + tx;
      tTh[o] = hh;
      tTl[o] = (_Float16)(v - (float)hh);
    }
  }
}

// ---- K4: f = vpT @ t^T' via MFMA (per map, 3 K-parts). featT3[part][k][b]
__global__ __launch_bounds__(256) void k_f_gemm_mfma(const _Float16* __restrict__ vpTh, const _Float16* __restrict__ vpTl,
                                                     const _Float16* __restrict__ tTh, const _Float16* __restrict__ tTl,
                                                     float* __restrict__ featT3, int map){
  int wg = blockIdx.x;                 // 576 = 192 mbL * 3 parts
  int mbL = wg / 3, part = wg % 3;
  int b = mbL / 3, h = mbL % 3;
  __shared__ __align__(16) _Float16 Ah[80][40], Al[80][40], Bh[80][40], Bl[80][40];
  int t = threadIdx.x;
  int w4 = t >> 6, lane = t & 63, tx = lane & 15, hi = lane >> 4;
  const _Float16* Abh = vpTh + (size_t)(map * BHN + mbL) * 80 * NSEQ;
  const _Float16* Abl = vpTl + (size_t)(map * BHN + mbL) * 80 * NSEQ;
  const _Float16* Bbh = tTh + (size_t)mbL * 80 * NSEQ;
  const _Float16* Bbl = tTl + (size_t)mbL * 80 * NSEQ;
  f32x4 acc[7];
  #pragma unroll
  for (int j = 0; j < 7; ++j) acc[j] = (f32x4){0.f, 0.f, 0.f, 0.f};

  for (int kc = part * 6; kc < part * 6 + 6; ++kc){
    int c0 = kc * 32;
    __syncthreads();
    #pragma unroll
    for (int k2 = 0; k2 < 2; ++k2){
      int idx = t + 256 * k2;
      if (idx < 320){
        int row = idx >> 2, cc = (idx & 3) << 3;
        *(half8*)&Ah[row][cc] = *(const half8*)(Abh + (size_t)row * NSEQ + c0 + cc);
        *(half8*)&Al[row][cc] = *(const half8*)(Abl + (size_t)row * NSEQ + c0 + cc);
        *(half8*)&Bh[row][cc] = *(const half8*)(Bbh + (size_t)row * NSEQ + c0 + cc);
        *(half8*)&Bl[row][cc] = *(const half8*)(Bbl + (size_t)row * NSEQ + c0 + cc);
      }
    }
    __syncthreads();
    #pragma unroll
    for (int j = 0; j < 7; ++j){
      int ti = w4 + 4 * j;
      if (ti < 25){
        int db = ti / 5, eb = ti % 5;
        half8 ah = *(const half8*)&Ah[db * 16 + tx][hi * 8];
        half8 al = *(const half8*)&Al[db * 16 + tx][hi * 8];
        half8 bh = *(const half8*)&Bh[eb * 16 + tx][hi * 8];
        half8 bl = *(const half8*)&Bl[eb * 16 + tx][hi * 8];
        acc[j] = MFMA16(ah, bh, acc[j]);
        acc[j] = MFMA16(al, bh, acc[j]);
        acc[j] = MFMA16(ah, bl, acc[j]);
      }
    }
  }
  #pragma unroll
  for (int j = 0; j < 7; ++j){
    int ti = w4 + 4 * j;
    if (ti < 25){
      int db = ti / 5, eb = ti % 5;
      #pragma unroll
      for (int rr = 0; rr < 4; ++rr){
        int d = db * 16 + hi * 4 + rr, e = eb * 16 + tx;
        if (d < VP && e < VP)
          featT3[(size_t)part * 1881600 + (size_t)(map * 14700 + h * 4900 + d * VP + e) * 64 + b] = acc[j][rr];
      }
    }
  }
}

// ---- K4b: reduce 3 featT parts
__global__ __launch_bounds__(256) void k_feat_reduce(const float* __restrict__ featT3, float* __restrict__ featT){
  int gid = blockIdx.x * 256 + threadIdx.x;
  if (gid >= DIMSZ * 64) return;
  featT[gid] = featT3[gid] + featT3[1881600 + gid] + featT3[2 * 1881600 + gid];
}

// ---- K5: projection partials
__global__ __launch_bounds__(512) void k_proj_partial(const float* __restrict__ featT, const float* __restrict__ pw,
                                                      float* __restrict__ p){
  int ot = blockIdx.x & 7;
  int s  = blockIdx.x >> 3;            // 0..48
  int t = threadIdx.x;
  int b = t & 63, og = t >> 6;
  int obase = ot * 64 + og * 8;
  float acc[8] = {};
  int k0 = s * 600;
  for (int k = k0; k < k0 + 600; ++k){
    float fv = featT[(size_t)k * 64 + b];
    #pragma unroll
    for (int jj = 0; jj < 8; ++jj)
      acc[jj] += fv * pw[(size_t)(obase + jj) * DIMSZ + k];
  }
  #pragma unroll
  for (int jj = 0; jj < 8; ++jj)
    p[(size_t)s * 32768 + (size_t)(obase + jj) * 64 + b] = acc[jj];
}

// ---- K6: finalize
__global__ __launch_bounds__(256) void k_finalize(const float* __restrict__ p, const float* __restrict__ pb,
                                                  float* __restrict__ out){
  int gid = blockIdx.x * 256 + threadIdx.x;
  int o = gid & 511, b = gid >> 9;
  float s = pb[o];
  #pragma unroll
  for (int s2 = 0; s2 < 49; ++s2)
    s += p[(size_t)s2 * 32768 + (size_t)o * 64 + b];
  out[gid] = fmaxf(s, 0.0f);
}

extern "C" void kernel_launch(void* const* d_in, const int* in_sizes, int n_in,
                              void* d_out, int out_size, void* d_ws, size_t ws_size,
                              hipStream_t stream) {
  const float* x1   = (const float*)d_in[0];
  const float* x2   = (const float*)d_in[1];
  const float* lnw  = (const float*)d_in[2];
  const float* lnb  = (const float*)d_in[3];
  const float* qkvw = (const float*)d_in[4];
  const float* pw   = (const float*)d_in[5];
  const float* pb   = (const float*)d_in[6];
  float* out = (float*)d_out;

  float* w = (float*)d_ws;
  float*     mu      = w;                       // 73728
  float*     rstd    = w + 73728;               // 73728
  _Float16*  qh      = (_Float16*)(w + 147456);     // 28311552 halfs (14155776 f)
  _Float16*  ql      = (_Float16*)(w + 14303232);   // 14155776 f
  _Float16*  vpTh    = (_Float16*)(w + 28459008);   // 17694720 halfs (8847360 f)
  _Float16*  vpTl    = (_Float16*)(w + 37306368);   // 8847360 f
  _Float16*  tTh     = (_Float16*)(w + 46153728);   // per-map 8847360 halfs (4423680 f)
  _Float16*  tTl     = (_Float16*)(w + 50577408);   // 4423680 f
  float*     cs_part = w + 55001088;            // 1990656 (aliased by featT later)
  float*     featT   = w + 55001088;            // 1881600 (alias, used after cs_part dead)
  float*     rs      = w + 56991744;            // 221184
  float*     cs      = w + 57212928;            // 221184
  float*     featT3  = w + 57434112;            // 5644800
  float*     p       = w + 63078912;            // 1605632  -> total 64684544 f (~259 MB)

  k_ln_stats<<<384, 192, 0, stream>>>(x1, x2, mu, rstd);
  k_qkv_gemm_mfma<<<10368, 256, 0, stream>>>(x1, x2, mu, rstd, lnw, lnb, qkvw, qh, ql, vpTh, vpTl);
  k_pos_fill<<<13824, 256, 0, stream>>>(vpTh, vpTl);
  k_attn_stats_mfma<<<3456, 256, 0, stream>>>(qh, ql, rs, cs_part);
  k_cs_reduce<<<864, 256, 0, stream>>>(cs_part, cs);
  for (int map = 0; map < 2; ++map){
    k_apply_mfma<<<1728, 256, 0, stream>>>(qh, ql, vpTh, vpTl, rs, cs, tTh, tTl, map);
    k_f_gemm_mfma<<<576, 256, 0, stream>>>(vpTh, vpTl, tTh, tTl, featT3, map);
  }
  k_feat_reduce<<<7350, 256, 0, stream>>>(featT3, featT);
  k_proj_partial<<<392, 512, 0, stream>>>(featT, pw, p);
  k_finalize<<<128, 256, 0, stream>>>(p, pb, out);
}

// Round 4
// 763.615 us; speedup vs baseline: 2.8060x; 1.3325x over previous
//
#include <hip/hip_runtime.h>

#define NSEQ 576
#define CDIM 256
#define HEADS 3
#define HD 64
#define FEAT 192      // HEADS*HD
#define QKVF 576      // 3*FEAT
#define QK_F 384      // stored q,k cols
#define VP 70         // HD+6
#define BHN 192       // 64*3
#define DIMSZ 29400   // 2*3*70*70

typedef __attribute__((ext_vector_type(8))) _Float16 half8;
typedef __attribute__((ext_vector_type(4))) _Float16 half4;
typedef __attribute__((ext_vector_type(4))) float f32x4;

#define MFMA16(A,B,C) __builtin_amdgcn_mfma_f32_16x16x32_f16(A,B,C,0,0,0)

// positional encoding: pos[n] = {py^2, px^2, py*px, py, px, 1}
__device__ __forceinline__ float posval(int n, int pe){
  int yi = n % 24, xi = n / 24;
  float py = (float)yi * (2.0f/23.0f) - 1.0f;
  float px = (float)xi * (2.0f/23.0f) - 1.0f;
  switch(pe){
    case 0: return py*py;
    case 1: return px*px;
    case 2: return py*px;
    case 3: return py;
    case 4: return px;
    default: return 1.0f;
  }
}

// MFMA fragment with k-enum kappa(hi,i) = dbase + (i>>2)*16 + (i&3); LD = LDS row stride
template<int LD>
__device__ __forceinline__ half8 fragT(const _Float16 (*s)[LD], int row, int dbase){
  half4 a = *(const half4*)&s[row][dbase];
  half4 b = *(const half4*)&s[row][dbase + 16];
  return __builtin_shufflevector(a, b, 0, 1, 2, 3, 4, 5, 6, 7);
}

// copy 64 rows x 64 cols of f16 from global (row stride rstr halfs) into LDS [64][72]
__device__ __forceinline__ void stage_copy64(const _Float16* __restrict__ src, int rstr,
                                             _Float16 (*d)[72], int t){
  #pragma unroll
  for (int k2 = 0; k2 < 2; ++k2){
    int idx = t + 256 * k2;               // 512 chunks of 8 halfs
    int row = idx >> 3, c = (idx & 7) << 3;
    half8 v = *(const half8*)(src + (size_t)row * rstr + c);
    *(half4*)&d[row][c]     = (half4){v[0], v[1], v[2], v[3]};
    *(half4*)&d[row][c + 4] = (half4){v[4], v[5], v[6], v[7]};
  }
}

// ---- K0: LayerNorm stats
__global__ __launch_bounds__(192) void k_ln_stats(const float* __restrict__ x1, const float* __restrict__ x2,
                                                  float* __restrict__ mu, float* __restrict__ rstd){
  int idx = blockIdx.x;                 // 384
  int i2 = idx / 192;
  int rem = idx % 192;
  int b = rem / 3, ng = rem % 3;
  int n = ng * 192 + threadIdx.x;
  const float* x = i2 ? x2 : x1;
  const float* xb = x + (size_t)b * CDIM * NSEQ + n;
  float s = 0.f, sq = 0.f;
  for (int c = 0; c < CDIM; ++c){
    float v = xb[(size_t)c * NSEQ];
    s += v; sq += v * v;
  }
  float m = s * (1.0f/256.0f);
  float var = sq * (1.0f/256.0f) - m * m;
  int o = (i2 * 64 + b) * NSEQ + n;
  mu[o] = m;
  rstd[o] = rsqrtf(var + 1e-5f);
}

// ---- K1: fused LN + QKV GEMM via MFMA split-f16
__global__ __launch_bounds__(256) void k_qkv_gemm_mfma(const float* __restrict__ x1, const float* __restrict__ x2,
                                                       const float* __restrict__ mu, const float* __restrict__ rstd,
                                                       const float* __restrict__ lnw, const float* __restrict__ lnb,
                                                       const float* __restrict__ qkvw,
                                                       _Float16* __restrict__ qh, _Float16* __restrict__ ql,
                                                       _Float16* __restrict__ vpTh, _Float16* __restrict__ vpTl){
  int wg = (blockIdx.x & 7) * 1296 + (blockIdx.x >> 3);   // 10368 = 8*1296
  int ft = wg % 9;
  int mt = wg / 9;
  int ibn = mt * 64;
  int i2 = ibn / (64 * NSEQ);
  int bn = ibn % (64 * NSEQ);
  int b  = bn / NSEQ;
  int n0 = bn % NSEQ;
  const float* x = i2 ? x2 : x1;
  const float* xb = x + (size_t)b * CDIM * NSEQ + n0;
  __shared__ __align__(16) _Float16 Xh[64][68];
  __shared__ __align__(16) _Float16 Xl[64][68];
  __shared__ __align__(16) _Float16 Wh[64][68];
  __shared__ __align__(16) _Float16 Wl[64][68];
  __shared__ float smu[64], srstd[64], slnw[256], slnb[256];
  int t = threadIdx.x;
  int w = t >> 6, lane = t & 63, tx = lane & 15, hi = lane >> 4;
  if (t < 64){ smu[t] = mu[ibn + t]; srstd[t] = rstd[ibn + t]; }
  slnw[t] = lnw[t]; slnb[t] = lnb[t];

  f32x4 acc[4];
  #pragma unroll
  for (int s = 0; s < 4; ++s) acc[s] = (f32x4){0.f, 0.f, 0.f, 0.f};

  int nA = t & 63, cg = t >> 6;
  int fr = t >> 2, cq = t & 3;
  for (int c0 = 0; c0 < CDIM; c0 += 64){
    __syncthreads();
    float mun = smu[nA], rsn = srstd[nA];
    #pragma unroll
    for (int rr = 0; rr < 16; ++rr){
      int c = cg * 16 + rr;
      float v = xb[(size_t)(c0 + c) * NSEQ + nA];
      float xv = (v - mun) * rsn * slnw[c0 + c] + slnb[c0 + c];
      _Float16 hh = (_Float16)xv;
      Xh[nA][c] = hh;
      Xl[nA][c] = (_Float16)(xv - (float)hh);
    }
    const float* wp = qkvw + (size_t)(ft * 64 + fr) * CDIM + c0 + cq * 16;
    #pragma unroll
    for (int rr = 0; rr < 4; ++rr){
      float4 wv = *(const float4*)(wp + rr * 4);
      half4 h, l;
      h.x = (_Float16)wv.x; l.x = (_Float16)(wv.x - (float)h.x);
      h.y = (_Float16)wv.y; l.y = (_Float16)(wv.y - (float)h.y);
      h.z = (_Float16)wv.z; l.z = (_Float16)(wv.z - (float)h.z);
      h.w = (_Float16)wv.w; l.w = (_Float16)(wv.w - (float)h.w);
      *(half4*)&Wh[fr][cq * 16 + rr * 4] = h;
      *(half4*)&Wl[fr][cq * 16 + rr * 4] = l;
    }
    __syncthreads();
    #pragma unroll
    for (int kc = 0; kc < 2; ++kc){
      half8 wh = fragT<68>(Wh, w * 16 + tx, kc * 32 + hi * 4);
      half8 wl = fragT<68>(Wl, w * 16 + tx, kc * 32 + hi * 4);
      #pragma unroll
      for (int s = 0; s < 4; ++s){
        half8 xh = fragT<68>(Xh, s * 16 + tx, kc * 32 + hi * 4);
        half8 xl = fragT<68>(Xl, s * 16 + tx, kc * 32 + hi * 4);
        acc[s] = MFMA16(xh, wh, acc[s]);
        acc[s] = MFMA16(xl, wh, acc[s]);
        acc[s] = MFMA16(xh, wl, acc[s]);
      }
    }
  }
  if (ft < 6){
    #pragma unroll
    for (int s = 0; s < 4; ++s)
      #pragma unroll
      for (int rr = 0; rr < 4; ++rr){
        float v = acc[s][rr];
        _Float16 hh = (_Float16)v;
        size_t o = (size_t)(ibn + s * 16 + hi * 4 + rr) * QK_F + ft * 64 + w * 16 + tx;
        qh[o] = hh;
        ql[o] = (_Float16)(v - (float)hh);
      }
  } else {
    __syncthreads();
    #pragma unroll
    for (int s = 0; s < 4; ++s)
      #pragma unroll
      for (int rr = 0; rr < 4; ++rr){
        float v = acc[s][rr];
        _Float16 hh = (_Float16)v;
        Xh[s * 16 + hi * 4 + rr][w * 16 + tx] = hh;
        Xl[s * 16 + hi * 4 + rr][w * 16 + tx] = (_Float16)(v - (float)hh);
      }
    __syncthreads();
    int mbg = i2 * 192 + b * 3 + (ft - 6);
    #pragma unroll
    for (int it = 0; it < 16; ++it){
      int d = (t >> 6) + it * 4;
      int n2 = t & 63;
      size_t o = ((size_t)mbg * 80 + d) * NSEQ + n0 + n2;
      vpTh[o] = Xh[n2][d];
      vpTl[o] = Xl[n2][d];
    }
  }
}

// ---- K1b: fill vpT positional rows 64..79 (rows 70..79 zero)
__global__ __launch_bounds__(256) void k_pos_fill(_Float16* __restrict__ vpTh, _Float16* __restrict__ vpTl){
  int idx = blockIdx.x * 256 + threadIdx.x;
  if (idx >= 384 * 16 * NSEQ) return;
  int n = idx % NSEQ;
  int r = idx / NSEQ;
  int row = 64 + (r & 15);
  int mb = r >> 4;
  float v = 0.f;
  int pe = row - 64;
  if (pe < 6) v = posval(n, pe);
  _Float16 hh = (_Float16)v;
  size_t o = ((size_t)mb * 80 + row) * NSEQ + n;
  vpTh[o] = hh;
  vpTl[o] = (_Float16)(v - (float)hh);
}

// ---- K2: attention stats via MFMA
__global__ __launch_bounds__(256) void k_attn_stats_mfma(const _Float16* __restrict__ qh, const _Float16* __restrict__ ql,
                                                         float* __restrict__ rs, float* __restrict__ cs_part){
  int wg = (blockIdx.x & 7) * 432 + (blockIdx.x >> 3);   // 3456 = 8*432
  int map = wg / (BHN * 9);
  int r   = wg % (BHN * 9);
  int bh = r / 9, nt = r % 9;
  int b = bh / 3, h = bh % 3;
  int qi = 1 - map, ki = map;
  int mb = map * BHN + bh;
  const _Float16* qbh = qh + (size_t)((qi * 64 + b) * NSEQ) * QK_F + h * HD;
  const _Float16* qbl = ql + (size_t)((qi * 64 + b) * NSEQ) * QK_F + h * HD;
  const _Float16* kbh = qh + (size_t)((ki * 64 + b) * NSEQ) * QK_F + FEAT + h * HD;
  const _Float16* kbl = ql + (size_t)((ki * 64 + b) * NSEQ) * QK_F + FEAT + h * HD;
  int n0 = nt * 64;
  __shared__ __align__(16) _Float16 Ash[64][72];
  __shared__ __align__(16) _Float16 Asl[64][72];
  __shared__ float cpart[4][64];
  int t = threadIdx.x;
  int w = t >> 6, lane = t & 63, tx = lane & 15, hi = lane >> 4;

  stage_copy64(qbh + (size_t)n0 * QK_F, QK_F, Ash, t);
  stage_copy64(qbl + (size_t)n0 * QK_F, QK_F, Asl, t);
  __syncthreads();
  half8 qh0 = fragT<72>(Ash, w * 16 + tx, 0 + hi * 4);
  half8 qh1 = fragT<72>(Ash, w * 16 + tx, 32 + hi * 4);
  half8 ql0 = fragT<72>(Asl, w * 16 + tx, 0 + hi * 4);
  half8 ql1 = fragT<72>(Asl, w * 16 + tx, 32 + hi * 4);

  float rsum = 0.f;
  for (int mt = 0; mt < 9; ++mt){
    int m0 = mt * 64;
    __syncthreads();
    stage_copy64(kbh + (size_t)m0 * QK_F, QK_F, Ash, t);
    stage_copy64(kbl + (size_t)m0 * QK_F, QK_F, Asl, t);
    __syncthreads();
    f32x4 acc[4];
    #pragma unroll
    for (int s = 0; s < 4; ++s) acc[s] = (f32x4){0.f, 0.f, 0.f, 0.f};
    #pragma unroll
    for (int s = 0; s < 4; ++s){
      half8 kh0 = fragT<72>(Ash, s * 16 + tx, 0 + hi * 4);
      half8 kl0 = fragT<72>(Asl, s * 16 + tx, 0 + hi * 4);
      half8 kh1 = fragT<72>(Ash, s * 16 + tx, 32 + hi * 4);
      half8 kl1 = fragT<72>(Asl, s * 16 + tx, 32 + hi * 4);
      acc[s] = MFMA16(kh0, qh0, acc[s]);
      acc[s] = MFMA16(kl0, qh0, acc[s]);
      acc[s] = MFMA16(kh0, ql0, acc[s]);
      acc[s] = MFMA16(kh1, qh1, acc[s]);
      acc[s] = MFMA16(kl1, qh1, acc[s]);
      acc[s] = MFMA16(kh1, ql1, acc[s]);
    }
    #pragma unroll
    for (int s = 0; s < 4; ++s){
      #pragma unroll
      for (int rr = 0; rr < 4; ++rr){
        float e = __expf(acc[s][rr] * 0.125f);
        rsum += e;
        float c = e;
        c += __shfl_xor(c, 1);
        c += __shfl_xor(c, 2);
        c += __shfl_xor(c, 4);
        c += __shfl_xor(c, 8);
        if (tx == 0) cpart[w][s * 16 + hi * 4 + rr] = c;
      }
    }
    __syncthreads();
    if (t < 64){
      float s2 = cpart[0][t] + cpart[1][t] + cpart[2][t] + cpart[3][t];
      cs_part[((size_t)mb * 9 + nt) * NSEQ + m0 + t] = s2;
    }
  }
  rsum += __shfl_xor(rsum, 16);
  rsum += __shfl_xor(rsum, 32);
  if (lane < 16) rs[(size_t)mb * NSEQ + n0 + w * 16 + lane] = rsum;
}

// ---- K2b: reduce 9 col-sum partials -> cs
__global__ __launch_bounds__(256) void k_cs_reduce(const float* __restrict__ cs_part, float* __restrict__ cs){
  int tid = blockIdx.x * 256 + threadIdx.x;
  if (tid >= 2 * BHN * NSEQ) return;
  int mb = tid / NSEQ, m = tid % NSEQ;
  float s = 0.f;
  #pragma unroll
  for (int p = 0; p < 9; ++p)
    s += cs_part[((size_t)mb * 9 + p) * NSEQ + m];
  cs[tid] = s;
}

// ---- K3: apply pass via MFMA (per map). Writes t^T split-f16 [mbL][80][576].
__global__ __launch_bounds__(256) void k_apply_mfma(const _Float16* __restrict__ qh, const _Float16* __restrict__ ql,
                                                    const _Float16* __restrict__ vpTh, const _Float16* __restrict__ vpTl,
                                                    const float* __restrict__ rs, const float* __restrict__ cs,
                                                    _Float16* __restrict__ tTh, _Float16* __restrict__ tTl, int map){
  int wg = (blockIdx.x & 7) * 216 + (blockIdx.x >> 3);   // 1728 = 8*216
  int bh = wg / 9, nt = wg % 9;
  int b = bh / 3, h = bh % 3;
  int qi = 1 - map, ki = map;
  int mb = map * BHN + bh;
  const _Float16* qbh = qh + (size_t)((qi * 64 + b) * NSEQ) * QK_F + h * HD;
  const _Float16* qbl = ql + (size_t)((qi * 64 + b) * NSEQ) * QK_F + h * HD;
  const _Float16* kbh = qh + (size_t)((ki * 64 + b) * NSEQ) * QK_F + FEAT + h * HD;
  const _Float16* kbl = ql + (size_t)((ki * 64 + b) * NSEQ) * QK_F + FEAT + h * HD;
  const _Float16* vTh = vpTh + (size_t)mb * 80 * NSEQ;
  const _Float16* vTl = vpTl + (size_t)mb * 80 * NSEQ;
  int n0 = nt * 64;
  __shared__ __align__(16) _Float16 Ash[64][72];
  __shared__ __align__(16) _Float16 Asl[64][72];
  __shared__ __align__(16) _Float16 Vth[80][72];
  __shared__ __align__(16) _Float16 Vtl[80][72];
  __shared__ float cinv[64];
  int t = threadIdx.x;
  int w = t >> 6, lane = t & 63, tx = lane & 15, hi = lane >> 4;

  stage_copy64(qbh + (size_t)n0 * QK_F, QK_F, Ash, t);
  stage_copy64(qbl + (size_t)n0 * QK_F, QK_F, Asl, t);
  __syncthreads();
  half8 qh0 = fragT<72>(Ash, w * 16 + tx, 0 + hi * 4);
  half8 qh1 = fragT<72>(Ash, w * 16 + tx, 32 + hi * 4);
  half8 ql0 = fragT<72>(Asl, w * 16 + tx, 0 + hi * 4);
  half8 ql1 = fragT<72>(Asl, w * 16 + tx, 32 + hi * 4);
  float rinv = 1.0f / rs[(size_t)mb * NSEQ + n0 + w * 16 + tx];

  f32x4 tacc[5];
  #pragma unroll
  for (int et = 0; et < 5; ++et) tacc[et] = (f32x4){0.f, 0.f, 0.f, 0.f};

  for (int mt = 0; mt < 9; ++mt){
    int m0 = mt * 64;
    __syncthreads();
    stage_copy64(kbh + (size_t)m0 * QK_F, QK_F, Ash, t);
    stage_copy64(kbl + (size_t)m0 * QK_F, QK_F, Asl, t);
    #pragma unroll
    for (int k2 = 0; k2 < 3; ++k2){
      int idx = t + 256 * k2;
      if (idx < 640){
        int row = idx >> 3, c = (idx & 7) << 3;
        half8 v1 = *(const half8*)(vTh + (size_t)row * NSEQ + m0 + c);
        *(half4*)&Vth[row][c]     = (half4){v1[0], v1[1], v1[2], v1[3]};
        *(half4*)&Vth[row][c + 4] = (half4){v1[4], v1[5], v1[6], v1[7]};
        half8 v2 = *(const half8*)(vTl + (size_t)row * NSEQ + m0 + c);
        *(half4*)&Vtl[row][c]     = (half4){v2[0], v2[1], v2[2], v2[3]};
        *(half4*)&Vtl[row][c + 4] = (half4){v2[4], v2[5], v2[6], v2[7]};
      }
    }
    if (t < 64) cinv[t] = 1.0f / cs[(size_t)mb * NSEQ + m0 + t];
    __syncthreads();

    f32x4 acc[4];
    #pragma unroll
    for (int s = 0; s < 4; ++s) acc[s] = (f32x4){0.f, 0.f, 0.f, 0.f};
    #pragma unroll
    for (int s = 0; s < 4; ++s){
      half8 kh0 = fragT<72>(Ash, s * 16 + tx, 0 + hi * 4);
      half8 kl0 = fragT<72>(Asl, s * 16 + tx, 0 + hi * 4);
      half8 kh1 = fragT<72>(Ash, s * 16 + tx, 32 + hi * 4);
      half8 kl1 = fragT<72>(Asl, s * 16 + tx, 32 + hi * 4);
      acc[s] = MFMA16(kh0, qh0, acc[s]);
      acc[s] = MFMA16(kl0, qh0, acc[s]);
      acc[s] = MFMA16(kh0, ql0, acc[s]);
      acc[s] = MFMA16(kh1, qh1, acc[s]);
      acc[s] = MFMA16(kl1, qh1, acc[s]);
      acc[s] = MFMA16(kh1, ql1, acc[s]);
    }
    half8 bhf[2], blf[2];
    #pragma unroll
    for (int s = 0; s < 4; ++s){
      #pragma unroll
      for (int rr = 0; rr < 4; ++rr){
        float e2 = __expf(acc[s][rr] * 0.25f);
        float af = e2 * rinv * cinv[s * 16 + hi * 4 + rr];
        _Float16 hh = (_Float16)af;
        _Float16 ll = (_Float16)(af - (float)hh);
        bhf[s >> 1][(s & 1) * 4 + rr] = hh;
        blf[s >> 1][(s & 1) * 4 + rr] = ll;
      }
    }
    #pragma unroll
    for (int et = 0; et < 5; ++et){
      #pragma unroll
      for (int mc = 0; mc < 2; ++mc){
        half8 vhf = fragT<72>(Vth, et * 16 + tx, mc * 32 + hi * 4);
        half8 vlf = fragT<72>(Vtl, et * 16 + tx, mc * 32 + hi * 4);
        tacc[et] = MFMA16(vhf, bhf[mc], tacc[et]);
        tacc[et] = MFMA16(vhf, blf[mc], tacc[et]);
        tacc[et] = MFMA16(vlf, bhf[mc], tacc[et]);
      }
    }
  }
  #pragma unroll
  for (int et = 0; et < 5; ++et){
    #pragma unroll
    for (int rr = 0; rr < 4; ++rr){
      int e = et * 16 + hi * 4 + rr;
      float v = tacc[et][rr];
      _Float16 hh = (_Float16)v;
      size_t o = ((size_t)bh * 80 + e) * NSEQ + n0 + w * 16 + tx;
      tTh[o] = hh;
      tTl[o] = (_Float16)(v - (float)hh);
    }
  }
}

// ---- K4: f = vpT @ t^T' via MFMA (per map, 3 K-parts). featT3[part][k][b]
__global__ __launch_bounds__(256) void k_f_gemm_mfma(const _Float16* __restrict__ vpTh, const _Float16* __restrict__ vpTl,
                                                     const _Float16* __restrict__ tTh, const _Float16* __restrict__ tTl,
                                                     float* __restrict__ featT3, int map){
  int wg = blockIdx.x;                 // 576 = 192 mbL * 3 parts
  int mbL = wg / 3, part = wg % 3;
  int b = mbL / 3, h = mbL % 3;
  __shared__ __align__(16) _Float16 Ah[80][40], Al[80][40], Bh[80][40], Bl[80][40];
  int t = threadIdx.x;
  int w4 = t >> 6, lane = t & 63, tx = lane & 15, hi = lane >> 4;
  const _Float16* Abh = vpTh + (size_t)(map * BHN + mbL) * 80 * NSEQ;
  const _Float16* Abl = vpTl + (size_t)(map * BHN + mbL) * 80 * NSEQ;
  const _Float16* Bbh = tTh + (size_t)mbL * 80 * NSEQ;
  const _Float16* Bbl = tTl + (size_t)mbL * 80 * NSEQ;
  f32x4 acc[7];
  #pragma unroll
  for (int j = 0; j < 7; ++j) acc[j] = (f32x4){0.f, 0.f, 0.f, 0.f};

  for (int kc = part * 6; kc < part * 6 + 6; ++kc){
    int c0 = kc * 32;
    __syncthreads();
    #pragma unroll
    for (int k2 = 0; k2 < 2; ++k2){
      int idx = t + 256 * k2;
      if (idx < 320){
        int row = idx >> 2, cc = (idx & 3) << 3;
        *(half8*)&Ah[row][cc] = *(const half8*)(Abh + (size_t)row * NSEQ + c0 + cc);
        *(half8*)&Al[row][cc] = *(const half8*)(Abl + (size_t)row * NSEQ + c0 + cc);
        *(half8*)&Bh[row][cc] = *(const half8*)(Bbh + (size_t)row * NSEQ + c0 + cc);
        *(half8*)&Bl[row][cc] = *(const half8*)(Bbl + (size_t)row * NSEQ + c0 + cc);
      }
    }
    __syncthreads();
    #pragma unroll
    for (int j = 0; j < 7; ++j){
      int ti = w4 + 4 * j;
      if (ti < 25){
        int db = ti / 5, eb = ti % 5;
        half8 ah = *(const half8*)&Ah[db * 16 + tx][hi * 8];
        half8 al = *(const half8*)&Al[db * 16 + tx][hi * 8];
        half8 bh = *(const half8*)&Bh[eb * 16 + tx][hi * 8];
        half8 bl = *(const half8*)&Bl[eb * 16 + tx][hi * 8];
        acc[j] = MFMA16(ah, bh, acc[j]);
        acc[j] = MFMA16(al, bh, acc[j]);
        acc[j] = MFMA16(ah, bl, acc[j]);
      }
    }
  }
  #pragma unroll
  for (int j = 0; j < 7; ++j){
    int ti = w4 + 4 * j;
    if (ti < 25){
      int db = ti / 5, eb = ti % 5;
      #pragma unroll
      for (int rr = 0; rr < 4; ++rr){
        int d = db * 16 + hi * 4 + rr, e = eb * 16 + tx;
        if (d < VP && e < VP)
          featT3[(size_t)part * 1881600 + (size_t)(map * 14700 + h * 4900 + d * VP + e) * 64 + b] = acc[j][rr];
      }
    }
  }
}

// ---- K4b: reduce 3 featT parts
__global__ __launch_bounds__(256) void k_feat_reduce(const float* __restrict__ featT3, float* __restrict__ featT){
  int gid = blockIdx.x * 256 + threadIdx.x;
  if (gid >= DIMSZ * 64) return;
  featT[gid] = featT3[gid] + featT3[1881600 + gid] + featT3[2 * 1881600 + gid];
}

// ---- K5: projection GEMM. M=64(b) x N=512(o) x K=29400, tiled 64x64x300.
// grid 784 = 8 o-tiles x 98 K-slices; BK=20; 4x4 microtile.
// A = featT[k][b] (row k, col b contiguous); B = pw[o][k].
// partial out p[slice*4096 + b*64 + o_local] (slice = s*8+ot) for coalesced finalize.
__global__ __launch_bounds__(256) void k_proj_gemm(const float* __restrict__ featT, const float* __restrict__ pw,
                                                   float* __restrict__ p){
  int ot = blockIdx.x & 7;
  int s  = blockIdx.x >> 3;            // 0..97
  int o0 = ot * 64;
  int kbase = s * 300;
  __shared__ __align__(16) float As[20][72];
  __shared__ __align__(16) float Bs[20][72];
  int t = threadIdx.x, tx = t & 15, ty = t >> 4;
  float acc[4][4] = {};
  for (int kt = 0; kt < 15; ++kt){
    int k0 = kbase + kt * 20;
    __syncthreads();
    #pragma unroll
    for (int r = 0; r < 5; ++r){
      int idx = t + 256 * r;             // 1280 = 20*64
      int bb = idx & 63, kk = idx >> 6;  // As: coalesced across b
      As[kk][bb] = featT[(size_t)(k0 + kk) * 64 + bb];
      int ko = idx % 20, oo = idx / 20;  // Bs: 20 consecutive k per o-row
      Bs[ko][oo] = pw[(size_t)(o0 + oo) * DIMSZ + k0 + ko];
    }
    __syncthreads();
    #pragma unroll
    for (int k = 0; k < 20; ++k){
      float4 a4 = *(const float4*)&As[k][ty * 4];
      float4 b4 = *(const float4*)&Bs[k][tx * 4];
      float aa[4] = {a4.x, a4.y, a4.z, a4.w};
      float bb[4] = {b4.x, b4.y, b4.z, b4.w};
      #pragma unroll
      for (int i = 0; i < 4; ++i)
        #pragma unroll
        for (int j = 0; j < 4; ++j)
          acc[i][j] += aa[i] * bb[j];
    }
  }
  int slice = s * 8 + ot;
  #pragma unroll
  for (int i = 0; i < 4; ++i){
    float4 st = make_float4(acc[i][0], acc[i][1], acc[i][2], acc[i][3]);
    *(float4*)&p[(size_t)slice * 4096 + (ty * 4 + i) * 64 + tx * 4] = st;
  }
}

// ---- K6: finalize: out[b][o] = relu(sum_s p[(s*8+ot)*4096 + b*64 + lo] + bias[o])
__global__ __launch_bounds__(256) void k_finalize(const float* __restrict__ p, const float* __restrict__ pb,
                                                  float* __restrict__ out){
  int gid = blockIdx.x * 256 + threadIdx.x;   // 32768 = b*512 + o
  int o = gid & 511, b = gid >> 9;
  int ot = o >> 6, lo = o & 63;
  float s = pb[o];
  for (int s2 = 0; s2 < 98; ++s2)
    s += p[(size_t)(s2 * 8 + ot) * 4096 + b * 64 + lo];
  out[gid] = fmaxf(s, 0.0f);
}

extern "C" void kernel_launch(void* const* d_in, const int* in_sizes, int n_in,
                              void* d_out, int out_size, void* d_ws, size_t ws_size,
                              hipStream_t stream) {
  const float* x1   = (const float*)d_in[0];
  const float* x2   = (const float*)d_in[1];
  const float* lnw  = (const float*)d_in[2];
  const float* lnb  = (const float*)d_in[3];
  const float* qkvw = (const float*)d_in[4];
  const float* pw   = (const float*)d_in[5];
  const float* pb   = (const float*)d_in[6];
  float* out = (float*)d_out;

  float* w = (float*)d_ws;
  float*     mu      = w;                       // 73728
  float*     rstd    = w + 73728;               // 73728
  _Float16*  qh      = (_Float16*)(w + 147456);     // 28311552 halfs (14155776 f)
  _Float16*  ql      = (_Float16*)(w + 14303232);   // 14155776 f
  _Float16*  vpTh    = (_Float16*)(w + 28459008);   // 8847360 f
  _Float16*  vpTl    = (_Float16*)(w + 37306368);   // 8847360 f
  _Float16*  tTh     = (_Float16*)(w + 46153728);   // 4423680 f
  _Float16*  tTl     = (_Float16*)(w + 50577408);   // 4423680 f
  float*     cs_part = w + 55001088;            // 1990656 (aliased by featT later)
  float*     featT   = w + 55001088;            // 1881600 (alias, used after cs_part dead)
  float*     rs      = w + 56991744;            // 221184
  float*     cs      = w + 57212928;            // 221184
  float*     featT3  = w + 57434112;            // 5644800
  float*     p       = w + 57434112;            // 3211264 (alias: featT3 dead after feat_reduce)
  // total 64684544 floats (~259 MB)

  k_ln_stats<<<384, 192, 0, stream>>>(x1, x2, mu, rstd);
  k_qkv_gemm_mfma<<<10368, 256, 0, stream>>>(x1, x2, mu, rstd, lnw, lnb, qkvw, qh, ql, vpTh, vpTl);
  k_pos_fill<<<13824, 256, 0, stream>>>(vpTh, vpTl);
  k_attn_stats_mfma<<<3456, 256, 0, stream>>>(qh, ql, rs, cs_part);
  k_cs_reduce<<<864, 256, 0, stream>>>(cs_part, cs);
  for (int map = 0; map < 2; ++map){
    k_apply_mfma<<<1728, 256, 0, stream>>>(qh, ql, vpTh, vpTl, rs, cs, tTh, tTl, map);
    k_f_gemm_mfma<<<576, 256, 0, stream>>>(vpTh, vpTl, tTh, tTl, featT3, map);
  }
  k_feat_reduce<<<7350, 256, 0, stream>>>(featT3, featT);
  k_proj_gemm<<<784, 256, 0, stream>>>(featT, pw, p);
  k_finalize<<<128, 256, 0, stream>>>(p, pb, out);
}